// Round 13
// baseline (220.043 us; speedup 1.0000x reference)
//
#include <hip/hip_runtime.h>
#include <hip/hip_bf16.h>
#include <math.h>

#define HDIM 1024
#define SEQ  2048
#define BATCH 2
#define NHEAD 16
#define HEADD 64

typedef short bf16x8 __attribute__((ext_vector_type(8)));
typedef float f32x4  __attribute__((ext_vector_type(4)));
typedef unsigned short u16x8 __attribute__((ext_vector_type(8)));
typedef unsigned short u16x4 __attribute__((ext_vector_type(4)));

__device__ __forceinline__ unsigned short f2bf(float f) {
    unsigned u = __float_as_uint(f);
    unsigned r = (u + 0x7FFFu + ((u >> 16) & 1u)) >> 16;
    return (unsigned short)r;
}
__device__ __forceinline__ unsigned pk2bf(float lo, float hi) {
    __hip_bfloat162 h = __float22bfloat162_rn(float2{lo, hi});
    unsigned r;
    __builtin_memcpy(&r, &h, 4);
    return r;
}
__device__ __forceinline__ float fexp2(float x) {
#if __has_builtin(__builtin_amdgcn_exp2f)
    return __builtin_amdgcn_exp2f(x);
#else
    return exp2f(x);
#endif
}
__device__ __forceinline__ float frcp(float x) {
#if __has_builtin(__builtin_amdgcn_rcpf)
    return __builtin_amdgcn_rcpf(x);
#else
    return 1.0f / x;
#endif
}
// Abramowitz-Stegun 7.1.26 erf, |err| < 1.5e-7 (exact at bf16 precision)
__device__ __forceinline__ float erf_fast(float x) {
    float ax = fabsf(x);
    float t = frcp(fmaf(0.3275911f, ax, 1.0f));
    float p = fmaf(t, 1.061405429f, -1.453152027f);
    p = fmaf(p, t, 1.421413741f);
    p = fmaf(p, t, -0.284496736f);
    p = fmaf(p, t, 0.254829592f);
    p *= t;
    float e = fexp2(ax * ax * -1.4426950408889634f);
    return copysignf(fmaf(-p, e, 1.0f), x);
}
__device__ __forceinline__ float gelu_f(float v) {
    return 0.5f * v * (1.0f + erf_fast(v * 0.70710678118654752f));
}
__device__ __forceinline__ void gld16(void* lds, const void* g) {
    __builtin_amdgcn_global_load_lds(
        (const __attribute__((address_space(1))) unsigned int*)(g),
        (__attribute__((address_space(3))) unsigned int*)(lds),
        16, 0, 0);
}

// swizzled element offset for row-major [*][64] bf16 tiles (128B rows, 8 chunks of 16B)
#define SWZ(row, chunk) (((row) * 64) + (((chunk) ^ ((row) & 7)) << 3))

// ---------------- LayerNorm: fp32 in, bf16 out ----------------
__global__ __launch_bounds__(256) void ln_kernel(const float* __restrict__ x,
                                                 const float* __restrict__ gw,
                                                 const float* __restrict__ bw,
                                                 unsigned short* __restrict__ y)
{
    int row = blockIdx.x;
    int t = threadIdx.x;
    const float* xr = x + (size_t)row * HDIM;
    float4 v = *(const float4*)(xr + t * 4);
    float s1 = v.x + v.y + v.z + v.w;
    float s2 = v.x * v.x + v.y * v.y + v.z * v.z + v.w * v.w;
#pragma unroll
    for (int m = 1; m < 64; m <<= 1) {
        s1 += __shfl_xor(s1, m);
        s2 += __shfl_xor(s2, m);
    }
    __shared__ float red[8];
    int wid = t >> 6;
    if ((t & 63) == 0) { red[wid * 2] = s1; red[wid * 2 + 1] = s2; }
    __syncthreads();
    if (t == 0) {
        float a = red[0] + red[2] + red[4] + red[6];
        float b = red[1] + red[3] + red[5] + red[7];
        red[0] = a; red[1] = b;
    }
    __syncthreads();
    float mu  = red[0] * (1.0f / HDIM);
    float var = red[1] * (1.0f / HDIM) - mu * mu;
    float rs  = rsqrtf(var + 1e-5f);
    float4 g4 = *(const float4*)(gw + t * 4);
    float4 b4 = *(const float4*)(bw + t * 4);
    ushort4 o;
    o.x = f2bf((v.x - mu) * rs * g4.x + b4.x);
    o.y = f2bf((v.y - mu) * rs * g4.y + b4.y);
    o.z = f2bf((v.z - mu) * rs * g4.z + b4.z);
    o.w = f2bf((v.w - mu) * rs * g4.w + b4.w);
    *(ushort4*)(y + (size_t)row * HDIM + t * 4) = o;
}

// ------- batched weight fp32 [K][N] -> bf16 transposed [N][K], all 4 weights -------
__global__ __launch_bounds__(256) void wconv_all(const float* __restrict__ Wq,
                                                 const float* __restrict__ Wo,
                                                 const float* __restrict__ W1,
                                                 const float* __restrict__ W2,
                                                 unsigned short* __restrict__ WqT,
                                                 unsigned short* __restrict__ WoT,
                                                 unsigned short* __restrict__ W1T,
                                                 unsigned short* __restrict__ W2T)
{
    int bid = blockIdx.x;
    const float* W; unsigned short* WT; int K, nx, idx;
    if (bid < 3072)      { W = Wq; WT = WqT; K = 1024; nx = 96;  idx = bid; }
    else if (bid < 4096) { W = Wo; WT = WoT; K = 1024; nx = 32;  idx = bid - 3072; }
    else if (bid < 8192) { W = W1; WT = W1T; K = 1024; nx = 128; idx = bid - 4096; }
    else                 { W = W2; WT = W2T; K = 4096; nx = 32;  idx = bid - 8192; }
    int N = nx * 32;
    int n0 = (idx % nx) * 32, k0 = (idx / nx) * 32;

    __shared__ float tile[32][33];
    int t = threadIdx.x, c = t & 31, r = t >> 5;
#pragma unroll
    for (int i = 0; i < 4; ++i)
        tile[r + 8 * i][c] = W[(size_t)(k0 + r + 8 * i) * N + n0 + c];
    __syncthreads();
#pragma unroll
    for (int i = 0; i < 4; ++i)
        WT[(size_t)(n0 + r + 8 * i) * K + k0 + c] = f2bf(tile[c][r + 8 * i]);
}

// ------------- MFMA GEMM 128x128: BK=64, dbuf LDS 64KB, 1 barrier/K-tile -------------
// Round-1 verified structure (0 bank conflicts), default block mapping.
// B-column interleave: lane's 4 ni-accumulators = 4 contiguous output columns
// -> vector epilogue (16 x ushort4/float4 stores).
template <int EPI>
__global__ __launch_bounds__(256, 2) void mgemm(const unsigned short* __restrict__ A,
                                                const unsigned short* __restrict__ BT,
                                                const float* __restrict__ bias,
                                                const float* __restrict__ resid,
                                                float* __restrict__ Cf,
                                                unsigned short* __restrict__ Cb,
                                                int M, int N, int K)
{
    __shared__ char smem[65536];   // [2 bufs][A 16KB | B 16KB]
    int t = threadIdx.x;
    int bn = blockIdx.x * 128, bm = blockIdx.y * 128;
    int l = t & 63, w = t >> 6;
    int wm = w >> 1, wn = w & 1;
    int lrow = l & 15, kq = l >> 4;

    f32x4 acc[4][4];
#pragma unroll
    for (int i = 0; i < 4; ++i)
#pragma unroll
        for (int j = 0; j < 4; ++j) acc[i][j] = {0.f, 0.f, 0.f, 0.f};

    const unsigned short* Ap[4];
    const unsigned short* Bp[4];
    int ld[4];
#pragma unroll
    for (int i = 0; i < 4; ++i) {
        int cid = i * 256 + t;
        int row = cid >> 3, c = cid & 7;
        int gc = (c ^ (row & 7)) << 3;
        Ap[i] = A + (size_t)(bm + row) * K + gc;
        // B-column interleave: LDS row -> permuted BT row
        int prow = (row & 64) + ((row & 15) << 2) + ((row >> 4) & 3);
        Bp[i] = BT + (size_t)(bn + prow) * K + gc;
        ld[i] = cid << 4;
    }

    int nt = K >> 6;
#pragma unroll
    for (int i = 0; i < 4; ++i) {
        gld16(smem + ld[i], Ap[i]);
        gld16(smem + 16384 + ld[i], Bp[i]);
    }
    __syncthreads();

    for (int tk = 0; tk < nt; ++tk) {
        int cur = (tk & 1) << 15;
        if (tk + 1 < nt) {
            int k0 = (tk + 1) << 6;
            int nxt = 32768 - cur;
#pragma unroll
            for (int i = 0; i < 4; ++i) {
                gld16(smem + nxt + ld[i], Ap[i] + k0);
                gld16(smem + nxt + 16384 + ld[i], Bp[i] + k0);
            }
        }
        const unsigned short* sA = (const unsigned short*)(smem + cur);
        const unsigned short* sB = (const unsigned short*)(smem + cur + 16384);
#pragma unroll
        for (int kk = 0; kk < 2; ++kk) {
            bf16x8 af[4], bv[4];
#pragma unroll
            for (int mi = 0; mi < 4; ++mi)
                af[mi] = *(const bf16x8*)(sA + SWZ(wm * 64 + mi * 16 + lrow, kk * 4 + kq));
#pragma unroll
            for (int ni = 0; ni < 4; ++ni)
                bv[ni] = *(const bf16x8*)(sB + SWZ(wn * 64 + ni * 16 + lrow, kk * 4 + kq));
#pragma unroll
            for (int mi = 0; mi < 4; ++mi)
#pragma unroll
                for (int ni = 0; ni < 4; ++ni)
                    acc[mi][ni] = __builtin_amdgcn_mfma_f32_16x16x32_bf16(af[mi], bv[ni], acc[mi][ni], 0, 0, 0);
        }
        __syncthreads();
    }

    int crow = (l >> 4) * 4;
    int ccol = l & 15;
    int gcolb = bn + wn * 64 + ccol * 4;   // 4 contiguous output columns
    float4 b4 = *(const float4*)(bias + gcolb);
#pragma unroll
    for (int mi = 0; mi < 4; ++mi) {
#pragma unroll
        for (int r = 0; r < 4; ++r) {
            int grow = bm + wm * 64 + mi * 16 + crow + r;
            size_t off = (size_t)grow * N + gcolb;
            float v0 = acc[mi][0][r] + b4.x;
            float v1 = acc[mi][1][r] + b4.y;
            float v2 = acc[mi][2][r] + b4.z;
            float v3 = acc[mi][3][r] + b4.w;
            if (EPI == 1) {
                float4 rr = *(const float4*)(resid + off);
                float4 o4 = {v0 + rr.x, v1 + rr.y, v2 + rr.z, v3 + rr.w};
                *(float4*)(Cf + off) = o4;
            } else {
                if (EPI == 2) {
                    v0 = gelu_f(v0); v1 = gelu_f(v1); v2 = gelu_f(v2); v3 = gelu_f(v3);
                }
                ushort4 o4 = {f2bf(v0), f2bf(v1), f2bf(v2), f2bf(v3)};
                *(ushort4*)(Cb + off) = o4;
            }
        }
    }
}

// ------------- MFMA GEMM 64x128: geometry-halved variant -------------
// 2 blocks/CU (LDS 48KB).  Used for N=1024 shapes (512 blocks = exact fill)
// and QKV (grid 24x64 = 1536 blocks = exactly 3 fills, no tail; the 128x128
// kernel gave 768 blocks = 1.5 fills -> trailing half-fill ran at 50% capacity).
template <int EPI>
__global__ __launch_bounds__(256, 2) void mgemm64(const unsigned short* __restrict__ A,
                                                  const unsigned short* __restrict__ BT,
                                                  const float* __restrict__ bias,
                                                  const float* __restrict__ resid,
                                                  float* __restrict__ Cf,
                                                  unsigned short* __restrict__ Cb,
                                                  int M, int N, int K)
{
    __shared__ char smem[49152];   // [2 bufs][A 8KB | B 16KB]
    int t = threadIdx.x;
    int bn = blockIdx.x * 128, bm = blockIdx.y * 64;
    int l = t & 63, w = t >> 6;       // 4 waves: 1M x 4N; per-wave C = 64x32
    int lrow = l & 15, kq = l >> 4;

    f32x4 acc[4][2];
#pragma unroll
    for (int i = 0; i < 4; ++i)
#pragma unroll
        for (int j = 0; j < 2; ++j) acc[i][j] = {0.f, 0.f, 0.f, 0.f};

    const unsigned short* Ap[2];
    int ldA[2];
#pragma unroll
    for (int i = 0; i < 2; ++i) {
        int cid = i * 256 + t;
        int row = cid >> 3, c = cid & 7;
        Ap[i] = A + (size_t)(bm + row) * K + ((c ^ (row & 7)) << 3);
        ldA[i] = cid << 4;
    }
    const unsigned short* Bp[4];
    int ldB[4];
#pragma unroll
    for (int i = 0; i < 4; ++i) {
        int cid = i * 256 + t;
        int row = cid >> 3, c = cid & 7;
        // 2-wide column interleave: LDS row (w*32 + ni*16 + lr) <- BT row (w*32 + lr*2 + ni)
        int prow = (row & ~31) + ((row & 15) << 1) + ((row >> 4) & 1);
        Bp[i] = BT + (size_t)(bn + prow) * K + ((c ^ (row & 7)) << 3);
        ldB[i] = cid << 4;
    }

    int nt = K >> 6;
#pragma unroll
    for (int i = 0; i < 2; ++i) gld16(smem + ldA[i], Ap[i]);
#pragma unroll
    for (int i = 0; i < 4; ++i) gld16(smem + 8192 + ldB[i], Bp[i]);
    __syncthreads();

    for (int tk = 0; tk < nt; ++tk) {
        int cur = (tk & 1) * 24576;
        if (tk + 1 < nt) {
            int k0 = (tk + 1) << 6;
            int nxt = 24576 - cur;
#pragma unroll
            for (int i = 0; i < 2; ++i) gld16(smem + nxt + ldA[i], Ap[i] + k0);
#pragma unroll
            for (int i = 0; i < 4; ++i) gld16(smem + nxt + 8192 + ldB[i], Bp[i] + k0);
        }
        const unsigned short* sA = (const unsigned short*)(smem + cur);
        const unsigned short* sB = (const unsigned short*)(smem + cur + 8192);
#pragma unroll
        for (int kk = 0; kk < 2; ++kk) {
            bf16x8 af[4], bv[2];
#pragma unroll
            for (int mi = 0; mi < 4; ++mi)
                af[mi] = *(const bf16x8*)(sA + SWZ(mi * 16 + lrow, kk * 4 + kq));
#pragma unroll
            for (int ni = 0; ni < 2; ++ni)
                bv[ni] = *(const bf16x8*)(sB + SWZ(w * 32 + ni * 16 + lrow, kk * 4 + kq));
#pragma unroll
            for (int mi = 0; mi < 4; ++mi)
#pragma unroll
                for (int ni = 0; ni < 2; ++ni)
                    acc[mi][ni] = __builtin_amdgcn_mfma_f32_16x16x32_bf16(af[mi], bv[ni], acc[mi][ni], 0, 0, 0);
        }
        __syncthreads();
    }

    int crow = (l >> 4) * 4;
    int ccol = l & 15;
    int gcolb = bn + w * 32 + ccol * 2;   // 2 contiguous output columns
    float2 b2 = *(const float2*)(bias + gcolb);
#pragma unroll
    for (int mi = 0; mi < 4; ++mi) {
#pragma unroll
        for (int r = 0; r < 4; ++r) {
            int grow = bm + mi * 16 + crow + r;
            size_t off = (size_t)grow * N + gcolb;
            float v0 = acc[mi][0][r] + b2.x;
            float v1 = acc[mi][1][r] + b2.y;
            if (EPI == 1) {
                float2 rr = *(const float2*)(resid + off);
                float2 o2 = {v0 + rr.x, v1 + rr.y};
                *(float2*)(Cf + off) = o2;
            } else {
                if (EPI == 2) { v0 = gelu_f(v0); v1 = gelu_f(v1); }
                *(unsigned*)(Cb + off) = pk2bf(v0, v1);
            }
        }
    }
}

// ---------------- MFMA flash attention v4 (round-9 best: 67.4us) ----------------
// 128 q-rows / 8 waves / block; reg-staged K+V prefetch across raw s_barrier;
// XCD pair-locality remap (FETCH 70->12MB).  Rounds 10-12 variants (setprio,
// tree-reduce, b64 P-write, K-gld16) all null or negative -> this exact form.
__global__ __launch_bounds__(512) void mattn(const unsigned short* __restrict__ qkv,
                                             unsigned short* __restrict__ out)
{
    __shared__ unsigned short Qs[128 * 64];       // [q][d] swizzled (16KB)
    __shared__ unsigned short Ks[2][64 * 64];     // [k][d] swizzled, dbuf (16KB)
    __shared__ unsigned short Vt[2][64 * 64];     // [d][k] swizzled, dbuf (16KB)
    __shared__ unsigned short Ps[8 * 16 * 64];    // per-wave [q16][k64] swizzled (16KB)
    int t = threadIdx.x;
    int w = t >> 6, l = t & 63;
    int lr = l & 15, lh = l >> 4;
    // XCD pair-locality remap (grid = 16 x 16 x 2 = 512 blocks, all co-resident)
    int hwid = blockIdx.x + (blockIdx.y << 4) + (blockIdx.z << 8);
    int xcd = hwid & 7, slot = hwid >> 3;
    int pair = (xcd << 2) + (slot >> 4);
    int q0 = (slot & 15) * 128;
    int hh = pair & 15, b = pair >> 4;
    const unsigned short* Qg = qkv + (size_t)b * SEQ * 3072 + hh * 64;
    const unsigned short* Kg = Qg + 1024;
    const unsigned short* Vg = Qg + 2048;

    // ---- stage Q via gld16 (pre-swizzled global source): 1024 chunks, 2/thread ----
#pragma unroll
    for (int i = 0; i < 2; ++i) {
        int chunkid = i * 512 + t;
        int row = chunkid >> 3, c = chunkid & 7;
        gld16(((char*)Qs) + chunkid * 16,
              Qg + (size_t)(q0 + row) * 3072 + ((c ^ (row & 7)) << 3));
    }

    // ---- K reg-staging: 512 chunks (64 rows x 8), 1 per thread ----
    int kr0 = t >> 3, kc0 = t & 7;
    const unsigned short* Kp0 = Kg + (size_t)kr0 * 3072 + kc0 * 8;
    int kd0 = SWZ(kr0, kc0);
    // ---- V: thread handles k-pair (vk,vk+1) x 4 d-elems ----
    int vk = (t & 31) * 2;
    int vd0 = ((t >> 5) & 15) * 4;
    const unsigned short* Vp0 = Vg + (size_t)vk * 3072 + vd0;
    const unsigned short* Vp1 = Vp0 + 3072;

    // prologue: load K/V tile 0 to regs
    u16x8 k0 = *(const u16x8*)Kp0;
    u16x4 v0 = *(const u16x4*)Vp0;
    u16x4 v1 = *(const u16x4*)Vp1;
    Kp0 += 64 * 3072; Vp0 += 64 * 3072; Vp1 += 64 * 3072;

    __syncthreads();   // Qs ready (full drain; prologue only)
    bf16x8 qa[2];
#pragma unroll
    for (int ks = 0; ks < 2; ++ks)
        qa[ks] = *(const bf16x8*)(Qs + SWZ(w * 16 + lr, ks * 4 + lh));

    // write tile 0 into buffer 0
    *(u16x8*)(Ks[0] + kd0) = k0;
#pragma unroll
    for (int j = 0; j < 4; ++j) {
        int d = vd0 + j;
        unsigned pack = (unsigned)(unsigned short)v0[j] | ((unsigned)(unsigned short)v1[j] << 16);
        *(unsigned*)(Vt[0] + SWZ(d, vk >> 3) + (vk & 7)) = pack;
    }
    // prefetch tile 1 to regs (stays in flight across the raw barrier)
    k0 = *(const u16x8*)Kp0;
    v0 = *(const u16x4*)Vp0; v1 = *(const u16x4*)Vp1;
    Kp0 += 64 * 3072; Vp0 += 64 * 3072; Vp1 += 64 * 3072;
    asm volatile("s_waitcnt lgkmcnt(0)" ::: "memory");   // publish buf0 writes
    __builtin_amdgcn_s_barrier();

    f32x4 o[4];
#pragma unroll
    for (int i = 0; i < 4; ++i) o[i] = {0.f, 0.f, 0.f, 0.f};
    float mr = -3.0e38f, lsum = 0.f;   // per-lane: q-row = w*16 + lr
    unsigned short* Pw = Ps + w * (16 * 64);
    const float C = 0.18033688011112042f;  // 0.125 * log2(e)

    const int nt = SEQ / 64;   // 32
    for (int tt = 0; tt < nt; ++tt) {
        const unsigned short* Kc = Ks[tt & 1];
        const unsigned short* Vc = Vt[tt & 1];

        // swapped QK^T: S^T = K·Q^T -> lane holds q=lr, k=ni*16+lh*4+r
        f32x4 s[4];
#pragma unroll
        for (int ni = 0; ni < 4; ++ni) s[ni] = {0.f, 0.f, 0.f, 0.f};
#pragma unroll
        for (int ks = 0; ks < 2; ++ks) {
#pragma unroll
            for (int ni = 0; ni < 4; ++ni) {
                bf16x8 kb = *(const bf16x8*)(Kc + SWZ(ni * 16 + lr, ks * 4 + lh));
                s[ni] = __builtin_amdgcn_mfma_f32_16x16x32_bf16(kb, qa[ks], s[ni], 0, 0, 0);
            }
        }
        // row max: 15 in-reg + 2 shfl (lanes sharing lr)
        float mx = s[0][0];
#pragma unroll
        for (int ni = 0; ni < 4; ++ni)
#pragma unroll
            for (int r = 0; r < 4; ++r) mx = fmaxf(mx, s[ni][r]);
        mx = fmaxf(mx, __shfl_xor(mx, 16));
        mx = fmaxf(mx, __shfl_xor(mx, 32));
        // defer-max: only rescale when growth beyond e^8 bound (always on tile 0)
        if (__any(mx > mr + 64.0f)) {
            float mn = fmaxf(mr, mx);
            float corr = fexp2((mr - mn) * C);
            mr = mn;
            lsum *= corr;
            float cr[4];
#pragma unroll
            for (int r = 0; r < 4; ++r) cr[r] = __shfl(corr, lh * 4 + r, 16);
#pragma unroll
            for (int nd = 0; nd < 4; ++nd) {
                o[nd][0] *= cr[0]; o[nd][1] *= cr[1];
                o[nd][2] *= cr[2]; o[nd][3] *= cr[3];
            }
        }
        float mc = mr * C;
        float rsum = 0.f;
#pragma unroll
        for (int ni = 0; ni < 4; ++ni)
#pragma unroll
            for (int r = 0; r < 4; ++r) {
                float p = fexp2(fmaf(s[ni][r], C, -mc));
                s[ni][r] = p;
                rsum += p;
            }
        rsum += __shfl_xor(rsum, 16);
        rsum += __shfl_xor(rsum, 32);
        lsum += rsum;
        // P write: packed pairs (adjacent k = r, r+1)
#pragma unroll
        for (int ni = 0; ni < 4; ++ni)
#pragma unroll
            for (int rp = 0; rp < 2; ++rp) {
                int k = ni * 16 + lh * 4 + rp * 2;
                *(unsigned*)(Pw + SWZ(lr, k >> 3) + (k & 7)) =
                    pk2bf(s[ni][rp * 2], s[ni][rp * 2 + 1]);
            }
        // PV: O[q16][d64] += P[q16][k64] @ V[k64][d64]
#pragma unroll
        for (int ks = 0; ks < 2; ++ks) {
            bf16x8 pa = *(const bf16x8*)(Pw + SWZ(lr, ks * 4 + lh));
#pragma unroll
            for (int nd = 0; nd < 4; ++nd) {
                bf16x8 vb = *(const bf16x8*)(Vc + SWZ(nd * 16 + lr, ks * 4 + lh));
                o[nd] = __builtin_amdgcn_mfma_f32_16x16x32_bf16(pa, vb, o[nd], 0, 0, 0);
            }
        }

        // ---- post-compute: write next tile's K/V (regs -> LDS), prefetch t+2 ----
        if (tt + 1 < nt) {
            int nb = (tt & 1) ^ 1;
            // implicit vmcnt wait here covers loads issued one full tile ago
            *(u16x8*)(Ks[nb] + kd0) = k0;
#pragma unroll
            for (int j = 0; j < 4; ++j) {
                int d = vd0 + j;
                unsigned pack = (unsigned)(unsigned short)v0[j] | ((unsigned)(unsigned short)v1[j] << 16);
                *(unsigned*)(Vt[nb] + SWZ(d, vk >> 3) + (vk & 7)) = pack;
            }
            if (tt + 2 < nt) {
                k0 = *(const u16x8*)Kp0;
                v0 = *(const u16x4*)Vp0; v1 = *(const u16x4*)Vp1;
                Kp0 += 64 * 3072; Vp0 += 64 * 3072; Vp1 += 64 * 3072;
            }
            asm volatile("s_waitcnt lgkmcnt(0)" ::: "memory");  // publish nb writes
            __builtin_amdgcn_s_barrier();                        // raw: no vmcnt drain
        }
    }
    // epilogue: redistribute 1/lsum to PV row owners
    float inv = 1.0f / lsum;
    float ir[4];
#pragma unroll
    for (int r = 0; r < 4; ++r) ir[r] = __shfl(inv, lh * 4 + r, 16);
#pragma unroll
    for (int r = 0; r < 4; ++r) {
        int q = q0 + w * 16 + lh * 4 + r;
#pragma unroll
        for (int nd = 0; nd < 4; ++nd) {
            int d = nd * 16 + lr;
            out[(size_t)((size_t)b * SEQ + q) * HDIM + hh * 64 + d] = f2bf(o[nd][r] * ir[r]);
        }
    }
}

extern "C" void kernel_launch(void* const* d_in, const int* in_sizes, int n_in,
                              void* d_out, int out_size, void* d_ws, size_t ws_size,
                              hipStream_t stream)
{
    const float* x     = (const float*)d_in[0];
    const float* ln1_g = (const float*)d_in[1];
    const float* ln1_b = (const float*)d_in[2];
    const float* W_qkv = (const float*)d_in[3];
    const float* b_qkv = (const float*)d_in[4];
    const float* W_out = (const float*)d_in[5];
    const float* b_out = (const float*)d_in[6];
    const float* ln2_g = (const float*)d_in[7];
    const float* ln2_b = (const float*)d_in[8];
    const float* W1    = (const float*)d_in[9];
    const float* b1    = (const float*)d_in[10];
    const float* W2    = (const float*)d_in[11];
    const float* b2    = (const float*)d_in[12];
    float* out = (float*)d_out;
    char* ws8  = (char*)d_ws;

    const int M = BATCH * SEQ;  // 4096
    const size_t MB = 1048576;

    unsigned short* hbuf = (unsigned short*)(ws8);
    unsigned short* qkvb = (unsigned short*)(ws8 + 8 * MB);
    unsigned short* attb = (unsigned short*)(ws8 + 32 * MB);
    unsigned short* ffn1 = (unsigned short*)(ws8 + 8 * MB);
    unsigned short* WqT  = (unsigned short*)(ws8 + 40 * MB);
    unsigned short* WoT  = (unsigned short*)(ws8 + 46 * MB);
    unsigned short* W1T  = (unsigned short*)(ws8 + 48 * MB);
    unsigned short* W2T  = (unsigned short*)(ws8 + 56 * MB);

    // all 4 weight conversions in one launch (12288 blocks)
    wconv_all<<<12288, 256, 0, stream>>>(W_qkv, W_out, W1, W2, WqT, WoT, W1T, W2T);

    ln_kernel<<<M, 256, 0, stream>>>(x, ln1_g, ln1_b, hbuf);
    // QKV: 64x128 variant, grid 24x64 = 1536 blocks = exactly 3 residency fills
    // (128x128 gave 768 = 1.5 fills -> 50%-idle tail on the second fill)
    mgemm64<0><<<dim3(3 * HDIM / 128, M / 64), 256, 0, stream>>>(hbuf, WqT, b_qkv, nullptr, nullptr, qkvb, M, 3 * HDIM, HDIM);
    mattn<<<dim3(SEQ / 128, NHEAD, BATCH), 512, 0, stream>>>(qkvb, attb);
    // out-proj: 64x128, grid 8x64 = 512 blocks (exact fill), fused residual
    mgemm64<1><<<dim3(HDIM / 128, M / 64), 256, 0, stream>>>(attb, WoT, b_out, x, out, nullptr, M, HDIM, HDIM);
    ln_kernel<<<M, 256, 0, stream>>>(out, ln2_g, ln2_b, hbuf);
    // FFN1: 128x128, grid 32x32 = 1024 blocks (2 exact fills), fused gelu
    mgemm<2><<<dim3(4 * HDIM / 128, M / 128), 256, 0, stream>>>(hbuf, W1T, b1, nullptr, nullptr, ffn1, M, 4 * HDIM, HDIM);
    // FFN2: 64x128, grid 8x64 = 512 blocks (exact fill), fused residual (in-place on out)
    mgemm64<1><<<dim3(HDIM / 128, M / 64), 256, 0, stream>>>(ffn1, W2T, b2, out, out, nullptr, M, HDIM, 4 * HDIM);
}

// Round 14
// 218.282 us; speedup vs baseline: 1.0081x; 1.0081x over previous
//
#include <hip/hip_runtime.h>
#include <hip/hip_bf16.h>
#include <math.h>

#define HDIM 1024
#define SEQ  2048
#define BATCH 2
#define NHEAD 16
#define HEADD 64

typedef short bf16x8 __attribute__((ext_vector_type(8)));
typedef float f32x4  __attribute__((ext_vector_type(4)));
typedef unsigned short u16x8 __attribute__((ext_vector_type(8)));
typedef unsigned short u16x4 __attribute__((ext_vector_type(4)));

__device__ __forceinline__ unsigned short f2bf(float f) {
    unsigned u = __float_as_uint(f);
    unsigned r = (u + 0x7FFFu + ((u >> 16) & 1u)) >> 16;
    return (unsigned short)r;
}
__device__ __forceinline__ unsigned pk2bf(float lo, float hi) {
    __hip_bfloat162 h = __float22bfloat162_rn(float2{lo, hi});
    unsigned r;
    __builtin_memcpy(&r, &h, 4);
    return r;
}
__device__ __forceinline__ float fexp2(float x) {
#if __has_builtin(__builtin_amdgcn_exp2f)
    return __builtin_amdgcn_exp2f(x);
#else
    return exp2f(x);
#endif
}
__device__ __forceinline__ float frcp(float x) {
#if __has_builtin(__builtin_amdgcn_rcpf)
    return __builtin_amdgcn_rcpf(x);
#else
    return 1.0f / x;
#endif
}
// Abramowitz-Stegun 7.1.26 erf, |err| < 1.5e-7 (exact at bf16 precision)
__device__ __forceinline__ float erf_fast(float x) {
    float ax = fabsf(x);
    float t = frcp(fmaf(0.3275911f, ax, 1.0f));
    float p = fmaf(t, 1.061405429f, -1.453152027f);
    p = fmaf(p, t, 1.421413741f);
    p = fmaf(p, t, -0.284496736f);
    p = fmaf(p, t, 0.254829592f);
    p *= t;
    float e = fexp2(ax * ax * -1.4426950408889634f);
    return copysignf(fmaf(-p, e, 1.0f), x);
}
__device__ __forceinline__ float gelu_f(float v) {
    return 0.5f * v * (1.0f + erf_fast(v * 0.70710678118654752f));
}
__device__ __forceinline__ void gld16(void* lds, const void* g) {
    __builtin_amdgcn_global_load_lds(
        (const __attribute__((address_space(1))) unsigned int*)(g),
        (__attribute__((address_space(3))) unsigned int*)(lds),
        16, 0, 0);
}

// swizzled element offset for row-major [*][64] bf16 tiles (128B rows, 8 chunks of 16B)
#define SWZ(row, chunk) (((row) * 64) + (((chunk) ^ ((row) & 7)) << 3))

// ---------------- LayerNorm: fp32 in, bf16 out ----------------
__global__ __launch_bounds__(256) void ln_kernel(const float* __restrict__ x,
                                                 const float* __restrict__ gw,
                                                 const float* __restrict__ bw,
                                                 unsigned short* __restrict__ y)
{
    int row = blockIdx.x;
    int t = threadIdx.x;
    const float* xr = x + (size_t)row * HDIM;
    float4 v = *(const float4*)(xr + t * 4);
    float s1 = v.x + v.y + v.z + v.w;
    float s2 = v.x * v.x + v.y * v.y + v.z * v.z + v.w * v.w;
#pragma unroll
    for (int m = 1; m < 64; m <<= 1) {
        s1 += __shfl_xor(s1, m);
        s2 += __shfl_xor(s2, m);
    }
    __shared__ float red[8];
    int wid = t >> 6;
    if ((t & 63) == 0) { red[wid * 2] = s1; red[wid * 2 + 1] = s2; }
    __syncthreads();
    if (t == 0) {
        float a = red[0] + red[2] + red[4] + red[6];
        float b = red[1] + red[3] + red[5] + red[7];
        red[0] = a; red[1] = b;
    }
    __syncthreads();
    float mu  = red[0] * (1.0f / HDIM);
    float var = red[1] * (1.0f / HDIM) - mu * mu;
    float rs  = rsqrtf(var + 1e-5f);
    float4 g4 = *(const float4*)(gw + t * 4);
    float4 b4 = *(const float4*)(bw + t * 4);
    ushort4 o;
    o.x = f2bf((v.x - mu) * rs * g4.x + b4.x);
    o.y = f2bf((v.y - mu) * rs * g4.y + b4.y);
    o.z = f2bf((v.z - mu) * rs * g4.z + b4.z);
    o.w = f2bf((v.w - mu) * rs * g4.w + b4.w);
    *(ushort4*)(y + (size_t)row * HDIM + t * 4) = o;
}

// ------- batched weight fp32 [K][N] -> bf16 transposed [N][K], all 4 weights -------
__global__ __launch_bounds__(256) void wconv_all(const float* __restrict__ Wq,
                                                 const float* __restrict__ Wo,
                                                 const float* __restrict__ W1,
                                                 const float* __restrict__ W2,
                                                 unsigned short* __restrict__ WqT,
                                                 unsigned short* __restrict__ WoT,
                                                 unsigned short* __restrict__ W1T,
                                                 unsigned short* __restrict__ W2T)
{
    int bid = blockIdx.x;
    const float* W; unsigned short* WT; int K, nx, idx;
    if (bid < 3072)      { W = Wq; WT = WqT; K = 1024; nx = 96;  idx = bid; }
    else if (bid < 4096) { W = Wo; WT = WoT; K = 1024; nx = 32;  idx = bid - 3072; }
    else if (bid < 8192) { W = W1; WT = W1T; K = 1024; nx = 128; idx = bid - 4096; }
    else                 { W = W2; WT = W2T; K = 4096; nx = 32;  idx = bid - 8192; }
    int N = nx * 32;
    int n0 = (idx % nx) * 32, k0 = (idx / nx) * 32;

    __shared__ float tile[32][33];
    int t = threadIdx.x, c = t & 31, r = t >> 5;
#pragma unroll
    for (int i = 0; i < 4; ++i)
        tile[r + 8 * i][c] = W[(size_t)(k0 + r + 8 * i) * N + n0 + c];
    __syncthreads();
#pragma unroll
    for (int i = 0; i < 4; ++i)
        WT[(size_t)(n0 + r + 8 * i) * K + k0 + c] = f2bf(tile[c][r + 8 * i]);
}

// ------------- MFMA GEMM 128x128: BK=64, dbuf LDS 64KB, 1 barrier/K-tile -------------
// Round-1 verified structure (0 bank conflicts), default block mapping.
// B-column interleave: lane's 4 ni-accumulators = 4 contiguous output columns
// -> vector epilogue (16 x ushort4/float4 stores).
template <int EPI>
__global__ __launch_bounds__(256, 2) void mgemm(const unsigned short* __restrict__ A,
                                                const unsigned short* __restrict__ BT,
                                                const float* __restrict__ bias,
                                                const float* __restrict__ resid,
                                                float* __restrict__ Cf,
                                                unsigned short* __restrict__ Cb,
                                                int M, int N, int K)
{
    __shared__ char smem[65536];   // [2 bufs][A 16KB | B 16KB]
    int t = threadIdx.x;
    int bn = blockIdx.x * 128, bm = blockIdx.y * 128;
    int l = t & 63, w = t >> 6;
    int wm = w >> 1, wn = w & 1;
    int lrow = l & 15, kq = l >> 4;

    f32x4 acc[4][4];
#pragma unroll
    for (int i = 0; i < 4; ++i)
#pragma unroll
        for (int j = 0; j < 4; ++j) acc[i][j] = {0.f, 0.f, 0.f, 0.f};

    const unsigned short* Ap[4];
    const unsigned short* Bp[4];
    int ld[4];
#pragma unroll
    for (int i = 0; i < 4; ++i) {
        int cid = i * 256 + t;
        int row = cid >> 3, c = cid & 7;
        int gc = (c ^ (row & 7)) << 3;
        Ap[i] = A + (size_t)(bm + row) * K + gc;
        // B-column interleave: LDS row -> permuted BT row
        int prow = (row & 64) + ((row & 15) << 2) + ((row >> 4) & 3);
        Bp[i] = BT + (size_t)(bn + prow) * K + gc;
        ld[i] = cid << 4;
    }

    int nt = K >> 6;
#pragma unroll
    for (int i = 0; i < 4; ++i) {
        gld16(smem + ld[i], Ap[i]);
        gld16(smem + 16384 + ld[i], Bp[i]);
    }
    __syncthreads();

    for (int tk = 0; tk < nt; ++tk) {
        int cur = (tk & 1) << 15;
        if (tk + 1 < nt) {
            int k0 = (tk + 1) << 6;
            int nxt = 32768 - cur;
#pragma unroll
            for (int i = 0; i < 4; ++i) {
                gld16(smem + nxt + ld[i], Ap[i] + k0);
                gld16(smem + nxt + 16384 + ld[i], Bp[i] + k0);
            }
        }
        const unsigned short* sA = (const unsigned short*)(smem + cur);
        const unsigned short* sB = (const unsigned short*)(smem + cur + 16384);
#pragma unroll
        for (int kk = 0; kk < 2; ++kk) {
            bf16x8 af[4], bv[4];
#pragma unroll
            for (int mi = 0; mi < 4; ++mi)
                af[mi] = *(const bf16x8*)(sA + SWZ(wm * 64 + mi * 16 + lrow, kk * 4 + kq));
#pragma unroll
            for (int ni = 0; ni < 4; ++ni)
                bv[ni] = *(const bf16x8*)(sB + SWZ(wn * 64 + ni * 16 + lrow, kk * 4 + kq));
#pragma unroll
            for (int mi = 0; mi < 4; ++mi)
#pragma unroll
                for (int ni = 0; ni < 4; ++ni)
                    acc[mi][ni] = __builtin_amdgcn_mfma_f32_16x16x32_bf16(af[mi], bv[ni], acc[mi][ni], 0, 0, 0);
        }
        __syncthreads();
    }

    int crow = (l >> 4) * 4;
    int ccol = l & 15;
    int gcolb = bn + wn * 64 + ccol * 4;   // 4 contiguous output columns
    float4 b4 = *(const float4*)(bias + gcolb);
#pragma unroll
    for (int mi = 0; mi < 4; ++mi) {
#pragma unroll
        for (int r = 0; r < 4; ++r) {
            int grow = bm + wm * 64 + mi * 16 + crow + r;
            size_t off = (size_t)grow * N + gcolb;
            float v0 = acc[mi][0][r] + b4.x;
            float v1 = acc[mi][1][r] + b4.y;
            float v2 = acc[mi][2][r] + b4.z;
            float v3 = acc[mi][3][r] + b4.w;
            if (EPI == 1) {
                float4 rr = *(const float4*)(resid + off);
                float4 o4 = {v0 + rr.x, v1 + rr.y, v2 + rr.z, v3 + rr.w};
                *(float4*)(Cf + off) = o4;
            } else {
                if (EPI == 2) {
                    v0 = gelu_f(v0); v1 = gelu_f(v1); v2 = gelu_f(v2); v3 = gelu_f(v3);
                }
                ushort4 o4 = {f2bf(v0), f2bf(v1), f2bf(v2), f2bf(v3)};
                *(ushort4*)(Cb + off) = o4;
            }
        }
    }
}

// ------------- MFMA GEMM 64x128: geometry-halved variant for N=1024 shapes -------------
// grid (8, M/64) = 512 blocks -> 2 blocks/CU.  LDS = 2 x (A 8KB + B 16KB) = 48KB.
template <int EPI>
__global__ __launch_bounds__(256, 2) void mgemm64(const unsigned short* __restrict__ A,
                                                  const unsigned short* __restrict__ BT,
                                                  const float* __restrict__ bias,
                                                  const float* __restrict__ resid,
                                                  float* __restrict__ Cf,
                                                  unsigned short* __restrict__ Cb,
                                                  int M, int N, int K)
{
    __shared__ char smem[49152];   // [2 bufs][A 8KB | B 16KB]
    int t = threadIdx.x;
    int bn = blockIdx.x * 128, bm = blockIdx.y * 64;
    int l = t & 63, w = t >> 6;       // 4 waves: 1M x 4N; per-wave C = 64x32
    int lrow = l & 15, kq = l >> 4;

    f32x4 acc[4][2];
#pragma unroll
    for (int i = 0; i < 4; ++i)
#pragma unroll
        for (int j = 0; j < 2; ++j) acc[i][j] = {0.f, 0.f, 0.f, 0.f};

    const unsigned short* Ap[2];
    int ldA[2];
#pragma unroll
    for (int i = 0; i < 2; ++i) {
        int cid = i * 256 + t;
        int row = cid >> 3, c = cid & 7;
        Ap[i] = A + (size_t)(bm + row) * K + ((c ^ (row & 7)) << 3);
        ldA[i] = cid << 4;
    }
    const unsigned short* Bp[4];
    int ldB[4];
#pragma unroll
    for (int i = 0; i < 4; ++i) {
        int cid = i * 256 + t;
        int row = cid >> 3, c = cid & 7;
        // 2-wide column interleave: LDS row (w*32 + ni*16 + lr) <- BT row (w*32 + lr*2 + ni)
        int prow = (row & ~31) + ((row & 15) << 1) + ((row >> 4) & 1);
        Bp[i] = BT + (size_t)(bn + prow) * K + ((c ^ (row & 7)) << 3);
        ldB[i] = cid << 4;
    }

    int nt = K >> 6;
#pragma unroll
    for (int i = 0; i < 2; ++i) gld16(smem + ldA[i], Ap[i]);
#pragma unroll
    for (int i = 0; i < 4; ++i) gld16(smem + 8192 + ldB[i], Bp[i]);
    __syncthreads();

    for (int tk = 0; tk < nt; ++tk) {
        int cur = (tk & 1) * 24576;
        if (tk + 1 < nt) {
            int k0 = (tk + 1) << 6;
            int nxt = 24576 - cur;
#pragma unroll
            for (int i = 0; i < 2; ++i) gld16(smem + nxt + ldA[i], Ap[i] + k0);
#pragma unroll
            for (int i = 0; i < 4; ++i) gld16(smem + nxt + 8192 + ldB[i], Bp[i] + k0);
        }
        const unsigned short* sA = (const unsigned short*)(smem + cur);
        const unsigned short* sB = (const unsigned short*)(smem + cur + 8192);
#pragma unroll
        for (int kk = 0; kk < 2; ++kk) {
            bf16x8 af[4], bv[2];
#pragma unroll
            for (int mi = 0; mi < 4; ++mi)
                af[mi] = *(const bf16x8*)(sA + SWZ(mi * 16 + lrow, kk * 4 + kq));
#pragma unroll
            for (int ni = 0; ni < 2; ++ni)
                bv[ni] = *(const bf16x8*)(sB + SWZ(w * 32 + ni * 16 + lrow, kk * 4 + kq));
#pragma unroll
            for (int mi = 0; mi < 4; ++mi)
#pragma unroll
                for (int ni = 0; ni < 2; ++ni)
                    acc[mi][ni] = __builtin_amdgcn_mfma_f32_16x16x32_bf16(af[mi], bv[ni], acc[mi][ni], 0, 0, 0);
        }
        __syncthreads();
    }

    int crow = (l >> 4) * 4;
    int ccol = l & 15;
    int gcolb = bn + w * 32 + ccol * 2;   // 2 contiguous output columns
    float2 b2 = *(const float2*)(bias + gcolb);
#pragma unroll
    for (int mi = 0; mi < 4; ++mi) {
#pragma unroll
        for (int r = 0; r < 4; ++r) {
            int grow = bm + mi * 16 + crow + r;
            size_t off = (size_t)grow * N + gcolb;
            float v0 = acc[mi][0][r] + b2.x;
            float v1 = acc[mi][1][r] + b2.y;
            if (EPI == 1) {
                float2 rr = *(const float2*)(resid + off);
                float2 o2 = {v0 + rr.x, v1 + rr.y};
                *(float2*)(Cf + off) = o2;
            } else {
                if (EPI == 2) { v0 = gelu_f(v0); v1 = gelu_f(v1); }
                *(unsigned*)(Cb + off) = pk2bf(v0, v1);
            }
        }
    }
}

// ------------- MFMA GEMM 256x256, 8-phase counted-vmcnt (T2+T3+T4+T5) -------------
// 8 waves (1M x 8N), per-wave C = 256x32.  LDS = 2 bufs x (A 32K | B 32K) = 128KB,
// 1 block/CU.  Half-tiles (16KB, 128 rows x BK=64 -> 128B rows, FULL 8-slot SWZ --
// fixes round-4's 64B-row degenerate swizzle): H0=B-low H1=B-high H2=A-low H3=A-high.
// Phase p of tile t: {ds_read A-frags mi in [4p,4p+4) (+B all at p==0) -> issue
// H(t+1,p) -> barrier -> lgkmcnt(0) -> setprio(1) 16 MFMA setprio(0) -> counted
// drain -> barrier}.  Drain proof (2 loads/half-tile, oldest-first):
//  end-of-p1: outstanding = H(t,3)+H(t+1,0)+H(t+1,1) = 6 -> vmcnt(4) retires
//    H(t,3) = A-high, needed first by p2.  Tail (t+1==nt): vmcnt(0).
//  end-of-p3: outstanding = H(t+1,0..3) = 8 -> vmcnt(2) retires B-low/B-high/
//    A-low of t+1 (needed by p0/p1), keeps its A-high in flight (T4: never 0).
// Prologue: stage t0, vmcnt(2) (A-high in flight), barrier -> identical steady state.
// WAR: H(t+1,*) targets the buffer last READ in tile t-1, one barrier earlier.
template <int EPI>
__global__ __launch_bounds__(512, 1) void mgemm8p(const unsigned short* __restrict__ A,
                                                  const unsigned short* __restrict__ BT,
                                                  const float* __restrict__ bias,
                                                  unsigned short* __restrict__ Cb,
                                                  int M, int N, int K)
{
    __shared__ char smem[131072];
    int t = threadIdx.x;
    int bn = blockIdx.x * 256, bm = blockIdx.y * 256;
    int l = t & 63, w = t >> 6;
    int lr = l & 15, kq = l >> 4;

    f32x4 acc[16][2];
#pragma unroll
    for (int i = 0; i < 16; ++i)
#pragma unroll
        for (int j = 0; j < 2; ++j) acc[i][j] = {0.f, 0.f, 0.f, 0.f};

    // staging geometry: half-tile = 128 rows x 8 chunks(16B) = 1024 chunks,
    // thread handles chunks t and t+512 (rows r0 and r0+64; same swizzled col g0).
    int r0 = t >> 3, c0 = t & 7;
    int g0 = (c0 ^ (r0 & 7)) << 3;
    const unsigned short* A0 = A + (size_t)(bm + r0) * K + g0;
    const unsigned short* A1 = A + (size_t)(bm + 64 + r0) * K + g0;
    const unsigned short* A2 = A + (size_t)(bm + 128 + r0) * K + g0;
    const unsigned short* A3 = A + (size_t)(bm + 192 + r0) * K + g0;
    // B 2-wide column interleave within 32-row groups (epilogue vectorization)
    int pr0 = (r0 & ~31) + ((r0 & 15) << 1) + ((r0 >> 4) & 1);
    const unsigned short* B0 = BT + (size_t)(bn + pr0) * K + g0;
    const unsigned short* B1 = BT + (size_t)(bn + 64 + pr0) * K + g0;
    const unsigned short* B2 = BT + (size_t)(bn + 128 + pr0) * K + g0;
    const unsigned short* B3 = BT + (size_t)(bn + 192 + pr0) * K + g0;
    int d0 = t << 4, d1 = d0 + 8192;

#define STG8(buf, h, tk) { \
        size_t ko_ = (size_t)(tk) << 6; \
        char* bb_ = smem + (buf) * 65536; \
        if ((h) == 0)      { gld16(bb_ + 32768 + d0, B0 + ko_); gld16(bb_ + 32768 + d1, B1 + ko_); } \
        else if ((h) == 1) { gld16(bb_ + 49152 + d0, B2 + ko_); gld16(bb_ + 49152 + d1, B3 + ko_); } \
        else if ((h) == 2) { gld16(bb_ + d0, A0 + ko_);         gld16(bb_ + d1, A1 + ko_); } \
        else               { gld16(bb_ + 16384 + d0, A2 + ko_); gld16(bb_ + 16384 + d1, A3 + ko_); } }

    int nt = K >> 6;
    // prologue: stage tile 0 (issue order H0,H1,H2,H3); keep A-high in flight
    STG8(0, 0, 0) STG8(0, 1, 0) STG8(0, 2, 0) STG8(0, 3, 0)
    asm volatile("s_waitcnt vmcnt(2)" ::: "memory");
    __builtin_amdgcn_s_barrier();

    for (int tt = 0; tt < nt; ++tt) {
        int cb = tt & 1, nb = cb ^ 1;
        bool pre = (tt + 1 < nt);
        const unsigned short* Ab = (const unsigned short*)(smem + cb * 65536);
        const unsigned short* Bb = (const unsigned short*)(smem + cb * 65536 + 32768);
        bf16x8 bfv[2][2];
#pragma unroll
        for (int p = 0; p < 4; ++p) {
            bf16x8 af[4][2];
#pragma unroll
            for (int m2 = 0; m2 < 4; ++m2)
#pragma unroll
                for (int kk = 0; kk < 2; ++kk)
                    af[m2][kk] = *(const bf16x8*)(Ab + SWZ((p * 4 + m2) * 16 + lr, kk * 4 + kq));
            if (p == 0) {
#pragma unroll
                for (int ni = 0; ni < 2; ++ni)
#pragma unroll
                    for (int kk = 0; kk < 2; ++kk)
                        bfv[ni][kk] = *(const bf16x8*)(Bb + SWZ(w * 32 + ni * 16 + lr, kk * 4 + kq));
            }
            if (pre) STG8(nb, p, tt + 1)
            __builtin_amdgcn_s_barrier();
            asm volatile("s_waitcnt lgkmcnt(0)" ::: "memory");
            __builtin_amdgcn_sched_barrier(0);
            __builtin_amdgcn_s_setprio(1);
#pragma unroll
            for (int m2 = 0; m2 < 4; ++m2)
#pragma unroll
                for (int ni = 0; ni < 2; ++ni)
#pragma unroll
                    for (int kk = 0; kk < 2; ++kk)
                        acc[p * 4 + m2][ni] = __builtin_amdgcn_mfma_f32_16x16x32_bf16(
                            af[m2][kk], bfv[ni][kk], acc[p * 4 + m2][ni], 0, 0, 0);
            __builtin_amdgcn_s_setprio(0);
            if (p == 1) {
                if (pre) asm volatile("s_waitcnt vmcnt(4)" ::: "memory");
                else     asm volatile("s_waitcnt vmcnt(0)" ::: "memory");
            }
            if (p == 3 && pre)
                asm volatile("s_waitcnt vmcnt(2)" ::: "memory");
            if (p < 3 || pre)
                __builtin_amdgcn_s_barrier();
        }
    }
#undef STG8

    int crow = (l >> 4) * 4;
    int ccol = l & 15;
    int gcolb = bn + w * 32 + ccol * 2;   // 2 contiguous output columns
    float2 b2 = *(const float2*)(bias + gcolb);
#pragma unroll
    for (int mi = 0; mi < 16; ++mi) {
#pragma unroll
        for (int r = 0; r < 4; ++r) {
            int grow = bm + mi * 16 + crow + r;
            size_t off = (size_t)grow * N + gcolb;
            float v0 = acc[mi][0][r] + b2.x;
            float v1 = acc[mi][1][r] + b2.y;
            if (EPI == 2) { v0 = gelu_f(v0); v1 = gelu_f(v1); }
            *(unsigned*)(Cb + off) = pk2bf(v0, v1);
        }
    }
}

// ---------------- MFMA flash attention v4 (round-9 best: 67.4us) ----------------
// 128 q-rows / 8 waves / block; reg-staged K+V prefetch across raw s_barrier;
// XCD pair-locality remap (FETCH 70->12MB).  Rounds 10-12 variants (setprio,
// tree-reduce, b64 P-write, K-gld16) all null or negative -> this exact form.
__global__ __launch_bounds__(512) void mattn(const unsigned short* __restrict__ qkv,
                                             unsigned short* __restrict__ out)
{
    __shared__ unsigned short Qs[128 * 64];       // [q][d] swizzled (16KB)
    __shared__ unsigned short Ks[2][64 * 64];     // [k][d] swizzled, dbuf (16KB)
    __shared__ unsigned short Vt[2][64 * 64];     // [d][k] swizzled, dbuf (16KB)
    __shared__ unsigned short Ps[8 * 16 * 64];    // per-wave [q16][k64] swizzled (16KB)
    int t = threadIdx.x;
    int w = t >> 6, l = t & 63;
    int lr = l & 15, lh = l >> 4;
    // XCD pair-locality remap (grid = 16 x 16 x 2 = 512 blocks, all co-resident)
    int hwid = blockIdx.x + (blockIdx.y << 4) + (blockIdx.z << 8);
    int xcd = hwid & 7, slot = hwid >> 3;
    int pair = (xcd << 2) + (slot >> 4);
    int q0 = (slot & 15) * 128;
    int hh = pair & 15, b = pair >> 4;
    const unsigned short* Qg = qkv + (size_t)b * SEQ * 3072 + hh * 64;
    const unsigned short* Kg = Qg + 1024;
    const unsigned short* Vg = Qg + 2048;

    // ---- stage Q via gld16 (pre-swizzled global source): 1024 chunks, 2/thread ----
#pragma unroll
    for (int i = 0; i < 2; ++i) {
        int chunkid = i * 512 + t;
        int row = chunkid >> 3, c = chunkid & 7;
        gld16(((char*)Qs) + chunkid * 16,
              Qg + (size_t)(q0 + row) * 3072 + ((c ^ (row & 7)) << 3));
    }

    // ---- K reg-staging: 512 chunks (64 rows x 8), 1 per thread ----
    int kr0 = t >> 3, kc0 = t & 7;
    const unsigned short* Kp0 = Kg + (size_t)kr0 * 3072 + kc0 * 8;
    int kd0 = SWZ(kr0, kc0);
    // ---- V: thread handles k-pair (vk,vk+1) x 4 d-elems ----
    int vk = (t & 31) * 2;
    int vd0 = ((t >> 5) & 15) * 4;
    const unsigned short* Vp0 = Vg + (size_t)vk * 3072 + vd0;
    const unsigned short* Vp1 = Vp0 + 3072;

    // prologue: load K/V tile 0 to regs
    u16x8 k0 = *(const u16x8*)Kp0;
    u16x4 v0 = *(const u16x4*)Vp0;
    u16x4 v1 = *(const u16x4*)Vp1;
    Kp0 += 64 * 3072; Vp0 += 64 * 3072; Vp1 += 64 * 3072;

    __syncthreads();   // Qs ready (full drain; prologue only)
    bf16x8 qa[2];
#pragma unroll
    for (int ks = 0; ks < 2; ++ks)
        qa[ks] = *(const bf16x8*)(Qs + SWZ(w * 16 + lr, ks * 4 + lh));

    // write tile 0 into buffer 0
    *(u16x8*)(Ks[0] + kd0) = k0;
#pragma unroll
    for (int j = 0; j < 4; ++j) {
        int d = vd0 + j;
        unsigned pack = (unsigned)(unsigned short)v0[j] | ((unsigned)(unsigned short)v1[j] << 16);
        *(unsigned*)(Vt[0] + SWZ(d, vk >> 3) + (vk & 7)) = pack;
    }
    // prefetch tile 1 to regs (stays in flight across the raw barrier)
    k0 = *(const u16x8*)Kp0;
    v0 = *(const u16x4*)Vp0; v1 = *(const u16x4*)Vp1;
    Kp0 += 64 * 3072; Vp0 += 64 * 3072; Vp1 += 64 * 3072;
    asm volatile("s_waitcnt lgkmcnt(0)" ::: "memory");   // publish buf0 writes
    __builtin_amdgcn_s_barrier();

    f32x4 o[4];
#pragma unroll
    for (int i = 0; i < 4; ++i) o[i] = {0.f, 0.f, 0.f, 0.f};
    float mr = -3.0e38f, lsum = 0.f;   // per-lane: q-row = w*16 + lr
    unsigned short* Pw = Ps + w * (16 * 64);
    const float C = 0.18033688011112042f;  // 0.125 * log2(e)

    const int nt = SEQ / 64;   // 32
    for (int tt = 0; tt < nt; ++tt) {
        const unsigned short* Kc = Ks[tt & 1];
        const unsigned short* Vc = Vt[tt & 1];

        // swapped QK^T: S^T = K·Q^T -> lane holds q=lr, k=ni*16+lh*4+r
        f32x4 s[4];
#pragma unroll
        for (int ni = 0; ni < 4; ++ni) s[ni] = {0.f, 0.f, 0.f, 0.f};
#pragma unroll
        for (int ks = 0; ks < 2; ++ks) {
#pragma unroll
            for (int ni = 0; ni < 4; ++ni) {
                bf16x8 kb = *(const bf16x8*)(Kc + SWZ(ni * 16 + lr, ks * 4 + lh));
                s[ni] = __builtin_amdgcn_mfma_f32_16x16x32_bf16(kb, qa[ks], s[ni], 0, 0, 0);
            }
        }
        // row max: 15 in-reg + 2 shfl (lanes sharing lr)
        float mx = s[0][0];
#pragma unroll
        for (int ni = 0; ni < 4; ++ni)
#pragma unroll
            for (int r = 0; r < 4; ++r) mx = fmaxf(mx, s[ni][r]);
        mx = fmaxf(mx, __shfl_xor(mx, 16));
        mx = fmaxf(mx, __shfl_xor(mx, 32));
        // defer-max: only rescale when growth beyond e^8 bound (always on tile 0)
        if (__any(mx > mr + 64.0f)) {
            float mn = fmaxf(mr, mx);
            float corr = fexp2((mr - mn) * C);
            mr = mn;
            lsum *= corr;
            float cr[4];
#pragma unroll
            for (int r = 0; r < 4; ++r) cr[r] = __shfl(corr, lh * 4 + r, 16);
#pragma unroll
            for (int nd = 0; nd < 4; ++nd) {
                o[nd][0] *= cr[0]; o[nd][1] *= cr[1];
                o[nd][2] *= cr[2]; o[nd][3] *= cr[3];
            }
        }
        float mc = mr * C;
        float rsum = 0.f;
#pragma unroll
        for (int ni = 0; ni < 4; ++ni)
#pragma unroll
            for (int r = 0; r < 4; ++r) {
                float p = fexp2(fmaf(s[ni][r], C, -mc));
                s[ni][r] = p;
                rsum += p;
            }
        rsum += __shfl_xor(rsum, 16);
        rsum += __shfl_xor(rsum, 32);
        lsum += rsum;
        // P write: packed pairs (adjacent k = r, r+1)
#pragma unroll
        for (int ni = 0; ni < 4; ++ni)
#pragma unroll
            for (int rp = 0; rp < 2; ++rp) {
                int k = ni * 16 + lh * 4 + rp * 2;
                *(unsigned*)(Pw + SWZ(lr, k >> 3) + (k & 7)) =
                    pk2bf(s[ni][rp * 2], s[ni][rp * 2 + 1]);
            }
        // PV: O[q16][d64] += P[q16][k64] @ V[k64][d64]
#pragma unroll
        for (int ks = 0; ks < 2; ++ks) {
            bf16x8 pa = *(const bf16x8*)(Pw + SWZ(lr, ks * 4 + lh));
#pragma unroll
            for (int nd = 0; nd < 4; ++nd) {
                bf16x8 vb = *(const bf16x8*)(Vc + SWZ(nd * 16 + lr, ks * 4 + lh));
                o[nd] = __builtin_amdgcn_mfma_f32_16x16x32_bf16(pa, vb, o[nd], 0, 0, 0);
            }
        }

        // ---- post-compute: write next tile's K/V (regs -> LDS), prefetch t+2 ----
        if (tt + 1 < nt) {
            int nb = (tt & 1) ^ 1;
            // implicit vmcnt wait here covers loads issued one full tile ago
            *(u16x8*)(Ks[nb] + kd0) = k0;
#pragma unroll
            for (int j = 0; j < 4; ++j) {
                int d = vd0 + j;
                unsigned pack = (unsigned)(unsigned short)v0[j] | ((unsigned)(unsigned short)v1[j] << 16);
                *(unsigned*)(Vt[nb] + SWZ(d, vk >> 3) + (vk & 7)) = pack;
            }
            if (tt + 2 < nt) {
                k0 = *(const u16x8*)Kp0;
                v0 = *(const u16x4*)Vp0; v1 = *(const u16x4*)Vp1;
                Kp0 += 64 * 3072; Vp0 += 64 * 3072; Vp1 += 64 * 3072;
            }
            asm volatile("s_waitcnt lgkmcnt(0)" ::: "memory");  // publish nb writes
            __builtin_amdgcn_s_barrier();                        // raw: no vmcnt drain
        }
    }
    // epilogue: redistribute 1/lsum to PV row owners
    float inv = 1.0f / lsum;
    float ir[4];
#pragma unroll
    for (int r = 0; r < 4; ++r) ir[r] = __shfl(inv, lh * 4 + r, 16);
#pragma unroll
    for (int r = 0; r < 4; ++r) {
        int q = q0 + w * 16 + lh * 4 + r;
#pragma unroll
        for (int nd = 0; nd < 4; ++nd) {
            int d = nd * 16 + lr;
            out[(size_t)((size_t)b * SEQ + q) * HDIM + hh * 64 + d] = f2bf(o[nd][r] * ir[r]);
        }
    }
}

extern "C" void kernel_launch(void* const* d_in, const int* in_sizes, int n_in,
                              void* d_out, int out_size, void* d_ws, size_t ws_size,
                              hipStream_t stream)
{
    const float* x     = (const float*)d_in[0];
    const float* ln1_g = (const float*)d_in[1];
    const float* ln1_b = (const float*)d_in[2];
    const float* W_qkv = (const float*)d_in[3];
    const float* b_qkv = (const float*)d_in[4];
    const float* W_out = (const float*)d_in[5];
    const float* b_out = (const float*)d_in[6];
    const float* ln2_g = (const float*)d_in[7];
    const float* ln2_b = (const float*)d_in[8];
    const float* W1    = (const float*)d_in[9];
    const float* b1    = (const float*)d_in[10];
    const float* W2    = (const float*)d_in[11];
    const float* b2    = (const float*)d_in[12];
    float* out = (float*)d_out;
    char* ws8  = (char*)d_ws;

    const int M = BATCH * SEQ;  // 4096
    const size_t MB = 1048576;

    unsigned short* hbuf = (unsigned short*)(ws8);
    unsigned short* qkvb = (unsigned short*)(ws8 + 8 * MB);
    unsigned short* attb = (unsigned short*)(ws8 + 32 * MB);
    unsigned short* ffn1 = (unsigned short*)(ws8 + 8 * MB);
    unsigned short* WqT  = (unsigned short*)(ws8 + 40 * MB);
    unsigned short* WoT  = (unsigned short*)(ws8 + 46 * MB);
    unsigned short* W1T  = (unsigned short*)(ws8 + 48 * MB);
    unsigned short* W2T  = (unsigned short*)(ws8 + 56 * MB);

    // all 4 weight conversions in one launch (12288 blocks)
    wconv_all<<<12288, 256, 0, stream>>>(W_qkv, W_out, W1, W2, WqT, WoT, W1T, W2T);

    ln_kernel<<<M, 256, 0, stream>>>(x, ln1_g, ln1_b, hbuf);
    // QKV: 128x128 (round-9 best config restored), grid 24x32 = 768 blocks
    mgemm<0><<<dim3(3 * HDIM / 128, M / 128), 256, 0, stream>>>(hbuf, WqT, b_qkv, nullptr, nullptr, qkvb, M, 3 * HDIM, HDIM);
    mattn<<<dim3(SEQ / 128, NHEAD, BATCH), 512, 0, stream>>>(qkvb, attb);
    // out-proj: 64x128, grid 8x64 = 512 blocks (exact fill), fused residual
    mgemm64<1><<<dim3(HDIM / 128, M / 64), 256, 0, stream>>>(attb, WoT, b_out, x, out, nullptr, M, HDIM, HDIM);
    ln_kernel<<<M, 256, 0, stream>>>(out, ln2_g, ln2_b, hbuf);
    // FFN1: 256x256 8-phase counted-vmcnt (grid 16x16 = 256 blocks = exact 1/CU fill), fused gelu
    mgemm8p<2><<<dim3(4 * HDIM / 256, M / 256), 512, 0, stream>>>(hbuf, W1T, b1, ffn1, M, 4 * HDIM, HDIM);
    // FFN2: 64x128, grid 8x64 = 512 blocks (exact fill), fused residual (in-place on out)
    mgemm64<1><<<dim3(HDIM / 128, M / 64), 256, 0, stream>>>(ffn1, W2T, b2, out, out, nullptr, M, HDIM, 4 * HDIM);
}

// Round 15
// 217.244 us; speedup vs baseline: 1.0129x; 1.0048x over previous
//
#include <hip/hip_runtime.h>
#include <hip/hip_bf16.h>
#include <math.h>

#define HDIM 1024
#define SEQ  2048
#define BATCH 2
#define NHEAD 16
#define HEADD 64

typedef short bf16x8 __attribute__((ext_vector_type(8)));
typedef float f32x4  __attribute__((ext_vector_type(4)));
typedef unsigned short u16x8 __attribute__((ext_vector_type(8)));
typedef unsigned short u16x4 __attribute__((ext_vector_type(4)));

__device__ __forceinline__ unsigned short f2bf(float f) {
    unsigned u = __float_as_uint(f);
    unsigned r = (u + 0x7FFFu + ((u >> 16) & 1u)) >> 16;
    return (unsigned short)r;
}
__device__ __forceinline__ unsigned pk2bf(float lo, float hi) {
    __hip_bfloat162 h = __float22bfloat162_rn(float2{lo, hi});
    unsigned r;
    __builtin_memcpy(&r, &h, 4);
    return r;
}
__device__ __forceinline__ float fexp2(float x) {
#if __has_builtin(__builtin_amdgcn_exp2f)
    return __builtin_amdgcn_exp2f(x);
#else
    return exp2f(x);
#endif
}
__device__ __forceinline__ float frcp(float x) {
#if __has_builtin(__builtin_amdgcn_rcpf)
    return __builtin_amdgcn_rcpf(x);
#else
    return 1.0f / x;
#endif
}
// Abramowitz-Stegun 7.1.26 erf, |err| < 1.5e-7 (exact at bf16 precision)
__device__ __forceinline__ float erf_fast(float x) {
    float ax = fabsf(x);
    float t = frcp(fmaf(0.3275911f, ax, 1.0f));
    float p = fmaf(t, 1.061405429f, -1.453152027f);
    p = fmaf(p, t, 1.421413741f);
    p = fmaf(p, t, -0.284496736f);
    p = fmaf(p, t, 0.254829592f);
    p *= t;
    float e = fexp2(ax * ax * -1.4426950408889634f);
    return copysignf(fmaf(-p, e, 1.0f), x);
}
__device__ __forceinline__ float gelu_f(float v) {
    return 0.5f * v * (1.0f + erf_fast(v * 0.70710678118654752f));
}
__device__ __forceinline__ void gld16(void* lds, const void* g) {
    __builtin_amdgcn_global_load_lds(
        (const __attribute__((address_space(1))) unsigned int*)(g),
        (__attribute__((address_space(3))) unsigned int*)(lds),
        16, 0, 0);
}

// swizzled element offset for row-major [*][64] bf16 tiles (128B rows, 8 chunks of 16B)
#define SWZ(row, chunk) (((row) * 64) + (((chunk) ^ ((row) & 7)) << 3))

// ---------------- LayerNorm: fp32 in, bf16 out ----------------
__global__ __launch_bounds__(256) void ln_kernel(const float* __restrict__ x,
                                                 const float* __restrict__ gw,
                                                 const float* __restrict__ bw,
                                                 unsigned short* __restrict__ y)
{
    int row = blockIdx.x;
    int t = threadIdx.x;
    const float* xr = x + (size_t)row * HDIM;
    float4 v = *(const float4*)(xr + t * 4);
    float s1 = v.x + v.y + v.z + v.w;
    float s2 = v.x * v.x + v.y * v.y + v.z * v.z + v.w * v.w;
#pragma unroll
    for (int m = 1; m < 64; m <<= 1) {
        s1 += __shfl_xor(s1, m);
        s2 += __shfl_xor(s2, m);
    }
    __shared__ float red[8];
    int wid = t >> 6;
    if ((t & 63) == 0) { red[wid * 2] = s1; red[wid * 2 + 1] = s2; }
    __syncthreads();
    if (t == 0) {
        float a = red[0] + red[2] + red[4] + red[6];
        float b = red[1] + red[3] + red[5] + red[7];
        red[0] = a; red[1] = b;
    }
    __syncthreads();
    float mu  = red[0] * (1.0f / HDIM);
    float var = red[1] * (1.0f / HDIM) - mu * mu;
    float rs  = rsqrtf(var + 1e-5f);
    float4 g4 = *(const float4*)(gw + t * 4);
    float4 b4 = *(const float4*)(bw + t * 4);
    ushort4 o;
    o.x = f2bf((v.x - mu) * rs * g4.x + b4.x);
    o.y = f2bf((v.y - mu) * rs * g4.y + b4.y);
    o.z = f2bf((v.z - mu) * rs * g4.z + b4.z);
    o.w = f2bf((v.w - mu) * rs * g4.w + b4.w);
    *(ushort4*)(y + (size_t)row * HDIM + t * 4) = o;
}

// ------- batched weight fp32 [K][N] -> bf16 transposed [N][K], all 4 weights -------
__global__ __launch_bounds__(256) void wconv_all(const float* __restrict__ Wq,
                                                 const float* __restrict__ Wo,
                                                 const float* __restrict__ W1,
                                                 const float* __restrict__ W2,
                                                 unsigned short* __restrict__ WqT,
                                                 unsigned short* __restrict__ WoT,
                                                 unsigned short* __restrict__ W1T,
                                                 unsigned short* __restrict__ W2T)
{
    int bid = blockIdx.x;
    const float* W; unsigned short* WT; int K, nx, idx;
    if (bid < 3072)      { W = Wq; WT = WqT; K = 1024; nx = 96;  idx = bid; }
    else if (bid < 4096) { W = Wo; WT = WoT; K = 1024; nx = 32;  idx = bid - 3072; }
    else if (bid < 8192) { W = W1; WT = W1T; K = 1024; nx = 128; idx = bid - 4096; }
    else                 { W = W2; WT = W2T; K = 4096; nx = 32;  idx = bid - 8192; }
    int N = nx * 32;
    int n0 = (idx % nx) * 32, k0 = (idx / nx) * 32;

    __shared__ float tile[32][33];
    int t = threadIdx.x, c = t & 31, r = t >> 5;
#pragma unroll
    for (int i = 0; i < 4; ++i)
        tile[r + 8 * i][c] = W[(size_t)(k0 + r + 8 * i) * N + n0 + c];
    __syncthreads();
#pragma unroll
    for (int i = 0; i < 4; ++i)
        WT[(size_t)(n0 + r + 8 * i) * K + k0 + c] = f2bf(tile[c][r + 8 * i]);
}

// ------------- MFMA GEMM 128x128: BK=64, dbuf LDS 64KB, 1 barrier/K-tile -------------
// Round-1 verified structure (0 bank conflicts), default block mapping.
// B-column interleave: lane's 4 ni-accumulators = 4 contiguous output columns
// -> vector epilogue (16 x ushort4/float4 stores).
template <int EPI>
__global__ __launch_bounds__(256, 2) void mgemm(const unsigned short* __restrict__ A,
                                                const unsigned short* __restrict__ BT,
                                                const float* __restrict__ bias,
                                                const float* __restrict__ resid,
                                                float* __restrict__ Cf,
                                                unsigned short* __restrict__ Cb,
                                                int M, int N, int K)
{
    __shared__ char smem[65536];   // [2 bufs][A 16KB | B 16KB]
    int t = threadIdx.x;
    int bn = blockIdx.x * 128, bm = blockIdx.y * 128;
    int l = t & 63, w = t >> 6;
    int wm = w >> 1, wn = w & 1;
    int lrow = l & 15, kq = l >> 4;

    f32x4 acc[4][4];
#pragma unroll
    for (int i = 0; i < 4; ++i)
#pragma unroll
        for (int j = 0; j < 4; ++j) acc[i][j] = {0.f, 0.f, 0.f, 0.f};

    const unsigned short* Ap[4];
    const unsigned short* Bp[4];
    int ld[4];
#pragma unroll
    for (int i = 0; i < 4; ++i) {
        int cid = i * 256 + t;
        int row = cid >> 3, c = cid & 7;
        int gc = (c ^ (row & 7)) << 3;
        Ap[i] = A + (size_t)(bm + row) * K + gc;
        // B-column interleave: LDS row -> permuted BT row
        int prow = (row & 64) + ((row & 15) << 2) + ((row >> 4) & 3);
        Bp[i] = BT + (size_t)(bn + prow) * K + gc;
        ld[i] = cid << 4;
    }

    int nt = K >> 6;
#pragma unroll
    for (int i = 0; i < 4; ++i) {
        gld16(smem + ld[i], Ap[i]);
        gld16(smem + 16384 + ld[i], Bp[i]);
    }
    __syncthreads();

    for (int tk = 0; tk < nt; ++tk) {
        int cur = (tk & 1) << 15;
        if (tk + 1 < nt) {
            int k0 = (tk + 1) << 6;
            int nxt = 32768 - cur;
#pragma unroll
            for (int i = 0; i < 4; ++i) {
                gld16(smem + nxt + ld[i], Ap[i] + k0);
                gld16(smem + nxt + 16384 + ld[i], Bp[i] + k0);
            }
        }
        const unsigned short* sA = (const unsigned short*)(smem + cur);
        const unsigned short* sB = (const unsigned short*)(smem + cur + 16384);
#pragma unroll
        for (int kk = 0; kk < 2; ++kk) {
            bf16x8 af[4], bv[4];
#pragma unroll
            for (int mi = 0; mi < 4; ++mi)
                af[mi] = *(const bf16x8*)(sA + SWZ(wm * 64 + mi * 16 + lrow, kk * 4 + kq));
#pragma unroll
            for (int ni = 0; ni < 4; ++ni)
                bv[ni] = *(const bf16x8*)(sB + SWZ(wn * 64 + ni * 16 + lrow, kk * 4 + kq));
#pragma unroll
            for (int mi = 0; mi < 4; ++mi)
#pragma unroll
                for (int ni = 0; ni < 4; ++ni)
                    acc[mi][ni] = __builtin_amdgcn_mfma_f32_16x16x32_bf16(af[mi], bv[ni], acc[mi][ni], 0, 0, 0);
        }
        __syncthreads();
    }

    int crow = (l >> 4) * 4;
    int ccol = l & 15;
    int gcolb = bn + wn * 64 + ccol * 4;   // 4 contiguous output columns
    float4 b4 = *(const float4*)(bias + gcolb);
#pragma unroll
    for (int mi = 0; mi < 4; ++mi) {
#pragma unroll
        for (int r = 0; r < 4; ++r) {
            int grow = bm + wm * 64 + mi * 16 + crow + r;
            size_t off = (size_t)grow * N + gcolb;
            float v0 = acc[mi][0][r] + b4.x;
            float v1 = acc[mi][1][r] + b4.y;
            float v2 = acc[mi][2][r] + b4.z;
            float v3 = acc[mi][3][r] + b4.w;
            if (EPI == 1) {
                float4 rr = *(const float4*)(resid + off);
                float4 o4 = {v0 + rr.x, v1 + rr.y, v2 + rr.z, v3 + rr.w};
                *(float4*)(Cf + off) = o4;
            } else {
                if (EPI == 2) {
                    v0 = gelu_f(v0); v1 = gelu_f(v1); v2 = gelu_f(v2); v3 = gelu_f(v3);
                }
                ushort4 o4 = {f2bf(v0), f2bf(v1), f2bf(v2), f2bf(v3)};
                *(ushort4*)(Cb + off) = o4;
            }
        }
    }
}

// ------------- MFMA GEMM 64x128: geometry-halved variant for N=1024 shapes -------------
// grid (8, M/64) = 512 blocks -> 2 blocks/CU.  LDS = 2 x (A 8KB + B 16KB) = 48KB.
template <int EPI>
__global__ __launch_bounds__(256, 2) void mgemm64(const unsigned short* __restrict__ A,
                                                  const unsigned short* __restrict__ BT,
                                                  const float* __restrict__ bias,
                                                  const float* __restrict__ resid,
                                                  float* __restrict__ Cf,
                                                  unsigned short* __restrict__ Cb,
                                                  int M, int N, int K)
{
    __shared__ char smem[49152];   // [2 bufs][A 8KB | B 16KB]
    int t = threadIdx.x;
    int bn = blockIdx.x * 128, bm = blockIdx.y * 64;
    int l = t & 63, w = t >> 6;       // 4 waves: 1M x 4N; per-wave C = 64x32
    int lrow = l & 15, kq = l >> 4;

    f32x4 acc[4][2];
#pragma unroll
    for (int i = 0; i < 4; ++i)
#pragma unroll
        for (int j = 0; j < 2; ++j) acc[i][j] = {0.f, 0.f, 0.f, 0.f};

    const unsigned short* Ap[2];
    int ldA[2];
#pragma unroll
    for (int i = 0; i < 2; ++i) {
        int cid = i * 256 + t;
        int row = cid >> 3, c = cid & 7;
        Ap[i] = A + (size_t)(bm + row) * K + ((c ^ (row & 7)) << 3);
        ldA[i] = cid << 4;
    }
    const unsigned short* Bp[4];
    int ldB[4];
#pragma unroll
    for (int i = 0; i < 4; ++i) {
        int cid = i * 256 + t;
        int row = cid >> 3, c = cid & 7;
        // 2-wide column interleave: LDS row (w*32 + ni*16 + lr) <- BT row (w*32 + lr*2 + ni)
        int prow = (row & ~31) + ((row & 15) << 1) + ((row >> 4) & 1);
        Bp[i] = BT + (size_t)(bn + prow) * K + ((c ^ (row & 7)) << 3);
        ldB[i] = cid << 4;
    }

    int nt = K >> 6;
#pragma unroll
    for (int i = 0; i < 2; ++i) gld16(smem + ldA[i], Ap[i]);
#pragma unroll
    for (int i = 0; i < 4; ++i) gld16(smem + 8192 + ldB[i], Bp[i]);
    __syncthreads();

    for (int tk = 0; tk < nt; ++tk) {
        int cur = (tk & 1) * 24576;
        if (tk + 1 < nt) {
            int k0 = (tk + 1) << 6;
            int nxt = 24576 - cur;
#pragma unroll
            for (int i = 0; i < 2; ++i) gld16(smem + nxt + ldA[i], Ap[i] + k0);
#pragma unroll
            for (int i = 0; i < 4; ++i) gld16(smem + nxt + 8192 + ldB[i], Bp[i] + k0);
        }
        const unsigned short* sA = (const unsigned short*)(smem + cur);
        const unsigned short* sB = (const unsigned short*)(smem + cur + 8192);
#pragma unroll
        for (int kk = 0; kk < 2; ++kk) {
            bf16x8 af[4], bv[2];
#pragma unroll
            for (int mi = 0; mi < 4; ++mi)
                af[mi] = *(const bf16x8*)(sA + SWZ(mi * 16 + lrow, kk * 4 + kq));
#pragma unroll
            for (int ni = 0; ni < 2; ++ni)
                bv[ni] = *(const bf16x8*)(sB + SWZ(w * 32 + ni * 16 + lrow, kk * 4 + kq));
#pragma unroll
            for (int mi = 0; mi < 4; ++mi)
#pragma unroll
                for (int ni = 0; ni < 2; ++ni)
                    acc[mi][ni] = __builtin_amdgcn_mfma_f32_16x16x32_bf16(af[mi], bv[ni], acc[mi][ni], 0, 0, 0);
        }
        __syncthreads();
    }

    int crow = (l >> 4) * 4;
    int ccol = l & 15;
    int gcolb = bn + w * 32 + ccol * 2;   // 2 contiguous output columns
    float2 b2 = *(const float2*)(bias + gcolb);
#pragma unroll
    for (int mi = 0; mi < 4; ++mi) {
#pragma unroll
        for (int r = 0; r < 4; ++r) {
            int grow = bm + mi * 16 + crow + r;
            size_t off = (size_t)grow * N + gcolb;
            float v0 = acc[mi][0][r] + b2.x;
            float v1 = acc[mi][1][r] + b2.y;
            if (EPI == 1) {
                float2 rr = *(const float2*)(resid + off);
                float2 o2 = {v0 + rr.x, v1 + rr.y};
                *(float2*)(Cf + off) = o2;
            } else {
                if (EPI == 2) { v0 = gelu_f(v0); v1 = gelu_f(v1); }
                *(unsigned*)(Cb + off) = pk2bf(v0, v1);
            }
        }
    }
}

// ---------------- MFMA flash attention v4 (best measured: 67.4us) ----------------
// 128 q-rows / 8 waves / block; reg-staged K+V prefetch across raw s_barrier;
// XCD pair-locality remap (FETCH 70->12MB).  Rounds 10-12 variants (setprio,
// tree-reduce, b64 P-write, K-gld16) all null or negative -> this exact form.
__global__ __launch_bounds__(512) void mattn(const unsigned short* __restrict__ qkv,
                                             unsigned short* __restrict__ out)
{
    __shared__ unsigned short Qs[128 * 64];       // [q][d] swizzled (16KB)
    __shared__ unsigned short Ks[2][64 * 64];     // [k][d] swizzled, dbuf (16KB)
    __shared__ unsigned short Vt[2][64 * 64];     // [d][k] swizzled, dbuf (16KB)
    __shared__ unsigned short Ps[8 * 16 * 64];    // per-wave [q16][k64] swizzled (16KB)
    int t = threadIdx.x;
    int w = t >> 6, l = t & 63;
    int lr = l & 15, lh = l >> 4;
    // XCD pair-locality remap (grid = 16 x 16 x 2 = 512 blocks, all co-resident)
    int hwid = blockIdx.x + (blockIdx.y << 4) + (blockIdx.z << 8);
    int xcd = hwid & 7, slot = hwid >> 3;
    int pair = (xcd << 2) + (slot >> 4);
    int q0 = (slot & 15) * 128;
    int hh = pair & 15, b = pair >> 4;
    const unsigned short* Qg = qkv + (size_t)b * SEQ * 3072 + hh * 64;
    const unsigned short* Kg = Qg + 1024;
    const unsigned short* Vg = Qg + 2048;

    // ---- stage Q via gld16 (pre-swizzled global source): 1024 chunks, 2/thread ----
#pragma unroll
    for (int i = 0; i < 2; ++i) {
        int chunkid = i * 512 + t;
        int row = chunkid >> 3, c = chunkid & 7;
        gld16(((char*)Qs) + chunkid * 16,
              Qg + (size_t)(q0 + row) * 3072 + ((c ^ (row & 7)) << 3));
    }

    // ---- K reg-staging: 512 chunks (64 rows x 8), 1 per thread ----
    int kr0 = t >> 3, kc0 = t & 7;
    const unsigned short* Kp0 = Kg + (size_t)kr0 * 3072 + kc0 * 8;
    int kd0 = SWZ(kr0, kc0);
    // ---- V: thread handles k-pair (vk,vk+1) x 4 d-elems ----
    int vk = (t & 31) * 2;
    int vd0 = ((t >> 5) & 15) * 4;
    const unsigned short* Vp0 = Vg + (size_t)vk * 3072 + vd0;
    const unsigned short* Vp1 = Vp0 + 3072;

    // prologue: load K/V tile 0 to regs
    u16x8 k0 = *(const u16x8*)Kp0;
    u16x4 v0 = *(const u16x4*)Vp0;
    u16x4 v1 = *(const u16x4*)Vp1;
    Kp0 += 64 * 3072; Vp0 += 64 * 3072; Vp1 += 64 * 3072;

    __syncthreads();   // Qs ready (full drain; prologue only)
    bf16x8 qa[2];
#pragma unroll
    for (int ks = 0; ks < 2; ++ks)
        qa[ks] = *(const bf16x8*)(Qs + SWZ(w * 16 + lr, ks * 4 + lh));

    // write tile 0 into buffer 0
    *(u16x8*)(Ks[0] + kd0) = k0;
#pragma unroll
    for (int j = 0; j < 4; ++j) {
        int d = vd0 + j;
        unsigned pack = (unsigned)(unsigned short)v0[j] | ((unsigned)(unsigned short)v1[j] << 16);
        *(unsigned*)(Vt[0] + SWZ(d, vk >> 3) + (vk & 7)) = pack;
    }
    // prefetch tile 1 to regs (stays in flight across the raw barrier)
    k0 = *(const u16x8*)Kp0;
    v0 = *(const u16x4*)Vp0; v1 = *(const u16x4*)Vp1;
    Kp0 += 64 * 3072; Vp0 += 64 * 3072; Vp1 += 64 * 3072;
    asm volatile("s_waitcnt lgkmcnt(0)" ::: "memory");   // publish buf0 writes
    __builtin_amdgcn_s_barrier();

    f32x4 o[4];
#pragma unroll
    for (int i = 0; i < 4; ++i) o[i] = {0.f, 0.f, 0.f, 0.f};
    float mr = -3.0e38f, lsum = 0.f;   // per-lane: q-row = w*16 + lr
    unsigned short* Pw = Ps + w * (16 * 64);
    const float C = 0.18033688011112042f;  // 0.125 * log2(e)

    const int nt = SEQ / 64;   // 32
    for (int tt = 0; tt < nt; ++tt) {
        const unsigned short* Kc = Ks[tt & 1];
        const unsigned short* Vc = Vt[tt & 1];

        // swapped QK^T: S^T = K·Q^T -> lane holds q=lr, k=ni*16+lh*4+r
        f32x4 s[4];
#pragma unroll
        for (int ni = 0; ni < 4; ++ni) s[ni] = {0.f, 0.f, 0.f, 0.f};
#pragma unroll
        for (int ks = 0; ks < 2; ++ks) {
#pragma unroll
            for (int ni = 0; ni < 4; ++ni) {
                bf16x8 kb = *(const bf16x8*)(Kc + SWZ(ni * 16 + lr, ks * 4 + lh));
                s[ni] = __builtin_amdgcn_mfma_f32_16x16x32_bf16(kb, qa[ks], s[ni], 0, 0, 0);
            }
        }
        // row max: 15 in-reg + 2 shfl (lanes sharing lr)
        float mx = s[0][0];
#pragma unroll
        for (int ni = 0; ni < 4; ++ni)
#pragma unroll
            for (int r = 0; r < 4; ++r) mx = fmaxf(mx, s[ni][r]);
        mx = fmaxf(mx, __shfl_xor(mx, 16));
        mx = fmaxf(mx, __shfl_xor(mx, 32));
        // defer-max: only rescale when growth beyond e^8 bound (always on tile 0)
        if (__any(mx > mr + 64.0f)) {
            float mn = fmaxf(mr, mx);
            float corr = fexp2((mr - mn) * C);
            mr = mn;
            lsum *= corr;
            float cr[4];
#pragma unroll
            for (int r = 0; r < 4; ++r) cr[r] = __shfl(corr, lh * 4 + r, 16);
#pragma unroll
            for (int nd = 0; nd < 4; ++nd) {
                o[nd][0] *= cr[0]; o[nd][1] *= cr[1];
                o[nd][2] *= cr[2]; o[nd][3] *= cr[3];
            }
        }
        float mc = mr * C;
        float rsum = 0.f;
#pragma unroll
        for (int ni = 0; ni < 4; ++ni)
#pragma unroll
            for (int r = 0; r < 4; ++r) {
                float p = fexp2(fmaf(s[ni][r], C, -mc));
                s[ni][r] = p;
                rsum += p;
            }
        rsum += __shfl_xor(rsum, 16);
        rsum += __shfl_xor(rsum, 32);
        lsum += rsum;
        // P write: packed pairs (adjacent k = r, r+1)
#pragma unroll
        for (int ni = 0; ni < 4; ++ni)
#pragma unroll
            for (int rp = 0; rp < 2; ++rp) {
                int k = ni * 16 + lh * 4 + rp * 2;
                *(unsigned*)(Pw + SWZ(lr, k >> 3) + (k & 7)) =
                    pk2bf(s[ni][rp * 2], s[ni][rp * 2 + 1]);
            }
        // PV: O[q16][d64] += P[q16][k64] @ V[k64][d64]
#pragma unroll
        for (int ks = 0; ks < 2; ++ks) {
            bf16x8 pa = *(const bf16x8*)(Pw + SWZ(lr, ks * 4 + lh));
#pragma unroll
            for (int nd = 0; nd < 4; ++nd) {
                bf16x8 vb = *(const bf16x8*)(Vc + SWZ(nd * 16 + lr, ks * 4 + lh));
                o[nd] = __builtin_amdgcn_mfma_f32_16x16x32_bf16(pa, vb, o[nd], 0, 0, 0);
            }
        }

        // ---- post-compute: write next tile's K/V (regs -> LDS), prefetch t+2 ----
        if (tt + 1 < nt) {
            int nb = (tt & 1) ^ 1;
            // implicit vmcnt wait here covers loads issued one full tile ago
            *(u16x8*)(Ks[nb] + kd0) = k0;
#pragma unroll
            for (int j = 0; j < 4; ++j) {
                int d = vd0 + j;
                unsigned pack = (unsigned)(unsigned short)v0[j] | ((unsigned)(unsigned short)v1[j] << 16);
                *(unsigned*)(Vt[nb] + SWZ(d, vk >> 3) + (vk & 7)) = pack;
            }
            if (tt + 2 < nt) {
                k0 = *(const u16x8*)Kp0;
                v0 = *(const u16x4*)Vp0; v1 = *(const u16x4*)Vp1;
                Kp0 += 64 * 3072; Vp0 += 64 * 3072; Vp1 += 64 * 3072;
            }
            asm volatile("s_waitcnt lgkmcnt(0)" ::: "memory");  // publish nb writes
            __builtin_amdgcn_s_barrier();                        // raw: no vmcnt drain
        }
    }
    // epilogue: redistribute 1/lsum to PV row owners
    float inv = 1.0f / lsum;
    float ir[4];
#pragma unroll
    for (int r = 0; r < 4; ++r) ir[r] = __shfl(inv, lh * 4 + r, 16);
#pragma unroll
    for (int r = 0; r < 4; ++r) {
        int q = q0 + w * 16 + lh * 4 + r;
#pragma unroll
        for (int nd = 0; nd < 4; ++nd) {
            int d = nd * 16 + lr;
            out[(size_t)((size_t)b * SEQ + q) * HDIM + hh * 64 + d] = f2bf(o[nd][r] * ir[r]);
        }
    }
}

extern "C" void kernel_launch(void* const* d_in, const int* in_sizes, int n_in,
                              void* d_out, int out_size, void* d_ws, size_t ws_size,
                              hipStream_t stream)
{
    const float* x     = (const float*)d_in[0];
    const float* ln1_g = (const float*)d_in[1];
    const float* ln1_b = (const float*)d_in[2];
    const float* W_qkv = (const float*)d_in[3];
    const float* b_qkv = (const float*)d_in[4];
    const float* W_out = (const float*)d_in[5];
    const float* b_out = (const float*)d_in[6];
    const float* ln2_g = (const float*)d_in[7];
    const float* ln2_b = (const float*)d_in[8];
    const float* W1    = (const float*)d_in[9];
    const float* b1    = (const float*)d_in[10];
    const float* W2    = (const float*)d_in[11];
    const float* b2    = (const float*)d_in[12];
    float* out = (float*)d_out;
    char* ws8  = (char*)d_ws;

    const int M = BATCH * SEQ;  // 4096
    const size_t MB = 1048576;

    unsigned short* hbuf = (unsigned short*)(ws8);
    unsigned short* qkvb = (unsigned short*)(ws8 + 8 * MB);
    unsigned short* attb = (unsigned short*)(ws8 + 32 * MB);
    unsigned short* ffn1 = (unsigned short*)(ws8 + 8 * MB);
    unsigned short* WqT  = (unsigned short*)(ws8 + 40 * MB);
    unsigned short* WoT  = (unsigned short*)(ws8 + 46 * MB);
    unsigned short* W1T  = (unsigned short*)(ws8 + 48 * MB);
    unsigned short* W2T  = (unsigned short*)(ws8 + 56 * MB);

    // all 4 weight conversions in one launch (12288 blocks)
    wconv_all<<<12288, 256, 0, stream>>>(W_qkv, W_out, W1, W2, WqT, WoT, W1T, W2T);

    ln_kernel<<<M, 256, 0, stream>>>(x, ln1_g, ln1_b, hbuf);
    // QKV: 128x128, grid 24x32 = 768 blocks
    mgemm<0><<<dim3(3 * HDIM / 128, M / 128), 256, 0, stream>>>(hbuf, WqT, b_qkv, nullptr, nullptr, qkvb, M, 3 * HDIM, HDIM);
    mattn<<<dim3(SEQ / 128, NHEAD, BATCH), 512, 0, stream>>>(qkvb, attb);
    // out-proj: 64x128, grid 8x64 = 512 blocks (exact fill), fused residual
    mgemm64<1><<<dim3(HDIM / 128, M / 64), 256, 0, stream>>>(attb, WoT, b_out, x, out, nullptr, M, HDIM, HDIM);
    ln_kernel<<<M, 256, 0, stream>>>(out, ln2_g, ln2_b, hbuf);
    // FFN1: 128x128, grid 32x32 = 1024 blocks (2 exact fills), fused gelu
    mgemm<2><<<dim3(4 * HDIM / 128, M / 128), 256, 0, stream>>>(hbuf, W1T, b1, nullptr, nullptr, ffn1, M, 4 * HDIM, HDIM);
    // FFN2: 64x128, grid 8x64 = 512 blocks (exact fill), fused residual (in-place on out)
    mgemm64<1><<<dim3(HDIM / 128, M / 64), 256, 0, stream>>>(ffn1, W2T, b2, out, out, nullptr, M, HDIM, 4 * HDIM);
}

// Round 16
// 216.692 us; speedup vs baseline: 1.0155x; 1.0025x over previous
//
#include <hip/hip_runtime.h>
#include <hip/hip_bf16.h>
#include <math.h>

#define HDIM 1024
#define SEQ  2048
#define BATCH 2
#define NHEAD 16
#define HEADD 64

typedef short bf16x8 __attribute__((ext_vector_type(8)));
typedef float f32x4  __attribute__((ext_vector_type(4)));
typedef unsigned short u16x8 __attribute__((ext_vector_type(8)));
typedef unsigned short u16x4 __attribute__((ext_vector_type(4)));

__device__ __forceinline__ unsigned short f2bf(float f) {
    unsigned u = __float_as_uint(f);
    unsigned r = (u + 0x7FFFu + ((u >> 16) & 1u)) >> 16;
    return (unsigned short)r;
}
__device__ __forceinline__ unsigned pk2bf(float lo, float hi) {
    __hip_bfloat162 h = __float22bfloat162_rn(float2{lo, hi});
    unsigned r;
    __builtin_memcpy(&r, &h, 4);
    return r;
}
__device__ __forceinline__ float fexp2(float x) {
#if __has_builtin(__builtin_amdgcn_exp2f)
    return __builtin_amdgcn_exp2f(x);
#else
    return exp2f(x);
#endif
}
__device__ __forceinline__ float frcp(float x) {
#if __has_builtin(__builtin_amdgcn_rcpf)
    return __builtin_amdgcn_rcpf(x);
#else
    return 1.0f / x;
#endif
}
// Abramowitz-Stegun 7.1.26 erf, |err| < 1.5e-7 (exact at bf16 precision)
__device__ __forceinline__ float erf_fast(float x) {
    float ax = fabsf(x);
    float t = frcp(fmaf(0.3275911f, ax, 1.0f));
    float p = fmaf(t, 1.061405429f, -1.453152027f);
    p = fmaf(p, t, 1.421413741f);
    p = fmaf(p, t, -0.284496736f);
    p = fmaf(p, t, 0.254829592f);
    p *= t;
    float e = fexp2(ax * ax * -1.4426950408889634f);
    return copysignf(fmaf(-p, e, 1.0f), x);
}
__device__ __forceinline__ float gelu_f(float v) {
    return 0.5f * v * (1.0f + erf_fast(v * 0.70710678118654752f));
}
__device__ __forceinline__ void gld16(void* lds, const void* g) {
    __builtin_amdgcn_global_load_lds(
        (const __attribute__((address_space(1))) unsigned int*)(g),
        (__attribute__((address_space(3))) unsigned int*)(lds),
        16, 0, 0);
}

// swizzled element offset for row-major [*][64] bf16 tiles (128B rows, 8 chunks of 16B)
#define SWZ(row, chunk) (((row) * 64) + (((chunk) ^ ((row) & 7)) << 3))

// ---------------- LayerNorm: fp32 in, bf16 out ----------------
__global__ __launch_bounds__(256) void ln_kernel(const float* __restrict__ x,
                                                 const float* __restrict__ gw,
                                                 const float* __restrict__ bw,
                                                 unsigned short* __restrict__ y)
{
    int row = blockIdx.x;
    int t = threadIdx.x;
    const float* xr = x + (size_t)row * HDIM;
    float4 v = *(const float4*)(xr + t * 4);
    float s1 = v.x + v.y + v.z + v.w;
    float s2 = v.x * v.x + v.y * v.y + v.z * v.z + v.w * v.w;
#pragma unroll
    for (int m = 1; m < 64; m <<= 1) {
        s1 += __shfl_xor(s1, m);
        s2 += __shfl_xor(s2, m);
    }
    __shared__ float red[8];
    int wid = t >> 6;
    if ((t & 63) == 0) { red[wid * 2] = s1; red[wid * 2 + 1] = s2; }
    __syncthreads();
    if (t == 0) {
        float a = red[0] + red[2] + red[4] + red[6];
        float b = red[1] + red[3] + red[5] + red[7];
        red[0] = a; red[1] = b;
    }
    __syncthreads();
    float mu  = red[0] * (1.0f / HDIM);
    float var = red[1] * (1.0f / HDIM) - mu * mu;
    float rs  = rsqrtf(var + 1e-5f);
    float4 g4 = *(const float4*)(gw + t * 4);
    float4 b4 = *(const float4*)(bw + t * 4);
    ushort4 o;
    o.x = f2bf((v.x - mu) * rs * g4.x + b4.x);
    o.y = f2bf((v.y - mu) * rs * g4.y + b4.y);
    o.z = f2bf((v.z - mu) * rs * g4.z + b4.z);
    o.w = f2bf((v.w - mu) * rs * g4.w + b4.w);
    *(ushort4*)(y + (size_t)row * HDIM + t * 4) = o;
}

// ------- merged prep: weight fp32->bf16^T (blocks 0..12287) + ln1 (blocks 12288..16383) ----
// Both depend only on kernel inputs -> fusing removes one serialized launch boundary.
__global__ __launch_bounds__(256) void prep_kernel(const float* __restrict__ Wq,
                                                   const float* __restrict__ Wo,
                                                   const float* __restrict__ W1,
                                                   const float* __restrict__ W2,
                                                   unsigned short* __restrict__ WqT,
                                                   unsigned short* __restrict__ WoT,
                                                   unsigned short* __restrict__ W1T,
                                                   unsigned short* __restrict__ W2T,
                                                   const float* __restrict__ x,
                                                   const float* __restrict__ gw,
                                                   const float* __restrict__ bw,
                                                   unsigned short* __restrict__ y)
{
    __shared__ float tile[32][33];
    int bid = blockIdx.x;
    int t = threadIdx.x;

    if (bid >= 12288) {
        // ---- LayerNorm row (x -> y), identical to ln_kernel ----
        int row = bid - 12288;
        const float* xr = x + (size_t)row * HDIM;
        float4 v = *(const float4*)(xr + t * 4);
        float s1 = v.x + v.y + v.z + v.w;
        float s2 = v.x * v.x + v.y * v.y + v.z * v.z + v.w * v.w;
#pragma unroll
        for (int m = 1; m < 64; m <<= 1) {
            s1 += __shfl_xor(s1, m);
            s2 += __shfl_xor(s2, m);
        }
        float* red = &tile[0][0];
        int wid = t >> 6;
        if ((t & 63) == 0) { red[wid * 2] = s1; red[wid * 2 + 1] = s2; }
        __syncthreads();
        if (t == 0) {
            float a = red[0] + red[2] + red[4] + red[6];
            float b = red[1] + red[3] + red[5] + red[7];
            red[0] = a; red[1] = b;
        }
        __syncthreads();
        float mu  = red[0] * (1.0f / HDIM);
        float var = red[1] * (1.0f / HDIM) - mu * mu;
        float rs  = rsqrtf(var + 1e-5f);
        float4 g4 = *(const float4*)(gw + t * 4);
        float4 b4 = *(const float4*)(bw + t * 4);
        ushort4 o;
        o.x = f2bf((v.x - mu) * rs * g4.x + b4.x);
        o.y = f2bf((v.y - mu) * rs * g4.y + b4.y);
        o.z = f2bf((v.z - mu) * rs * g4.z + b4.z);
        o.w = f2bf((v.w - mu) * rs * g4.w + b4.w);
        *(ushort4*)(y + (size_t)row * HDIM + t * 4) = o;
        return;
    }

    // ---- weight conversion tile, identical to wconv_all ----
    const float* W; unsigned short* WT; int K, nx, idx;
    if (bid < 3072)      { W = Wq; WT = WqT; K = 1024; nx = 96;  idx = bid; }
    else if (bid < 4096) { W = Wo; WT = WoT; K = 1024; nx = 32;  idx = bid - 3072; }
    else if (bid < 8192) { W = W1; WT = W1T; K = 1024; nx = 128; idx = bid - 4096; }
    else                 { W = W2; WT = W2T; K = 4096; nx = 32;  idx = bid - 8192; }
    int N = nx * 32;
    int n0 = (idx % nx) * 32, k0 = (idx / nx) * 32;

    int c = t & 31, r = t >> 5;
#pragma unroll
    for (int i = 0; i < 4; ++i)
        tile[r + 8 * i][c] = W[(size_t)(k0 + r + 8 * i) * N + n0 + c];
    __syncthreads();
#pragma unroll
    for (int i = 0; i < 4; ++i)
        WT[(size_t)(n0 + r + 8 * i) * K + k0 + c] = f2bf(tile[c][r + 8 * i]);
}

// ------------- MFMA GEMM 128x128: BK=64, dbuf LDS 64KB, 1 barrier/K-tile -------------
// Round-1 verified structure (0 bank conflicts), default block mapping.
// B-column interleave: lane's 4 ni-accumulators = 4 contiguous output columns
// -> vector epilogue (16 x ushort4/float4 stores).
template <int EPI>
__global__ __launch_bounds__(256, 2) void mgemm(const unsigned short* __restrict__ A,
                                                const unsigned short* __restrict__ BT,
                                                const float* __restrict__ bias,
                                                const float* __restrict__ resid,
                                                float* __restrict__ Cf,
                                                unsigned short* __restrict__ Cb,
                                                int M, int N, int K)
{
    __shared__ char smem[65536];   // [2 bufs][A 16KB | B 16KB]
    int t = threadIdx.x;
    int bn = blockIdx.x * 128, bm = blockIdx.y * 128;
    int l = t & 63, w = t >> 6;
    int wm = w >> 1, wn = w & 1;
    int lrow = l & 15, kq = l >> 4;

    f32x4 acc[4][4];
#pragma unroll
    for (int i = 0; i < 4; ++i)
#pragma unroll
        for (int j = 0; j < 4; ++j) acc[i][j] = {0.f, 0.f, 0.f, 0.f};

    const unsigned short* Ap[4];
    const unsigned short* Bp[4];
    int ld[4];
#pragma unroll
    for (int i = 0; i < 4; ++i) {
        int cid = i * 256 + t;
        int row = cid >> 3, c = cid & 7;
        int gc = (c ^ (row & 7)) << 3;
        Ap[i] = A + (size_t)(bm + row) * K + gc;
        // B-column interleave: LDS row -> permuted BT row
        int prow = (row & 64) + ((row & 15) << 2) + ((row >> 4) & 3);
        Bp[i] = BT + (size_t)(bn + prow) * K + gc;
        ld[i] = cid << 4;
    }

    int nt = K >> 6;
#pragma unroll
    for (int i = 0; i < 4; ++i) {
        gld16(smem + ld[i], Ap[i]);
        gld16(smem + 16384 + ld[i], Bp[i]);
    }
    __syncthreads();

    for (int tk = 0; tk < nt; ++tk) {
        int cur = (tk & 1) << 15;
        if (tk + 1 < nt) {
            int k0 = (tk + 1) << 6;
            int nxt = 32768 - cur;
#pragma unroll
            for (int i = 0; i < 4; ++i) {
                gld16(smem + nxt + ld[i], Ap[i] + k0);
                gld16(smem + nxt + 16384 + ld[i], Bp[i] + k0);
            }
        }
        const unsigned short* sA = (const unsigned short*)(smem + cur);
        const unsigned short* sB = (const unsigned short*)(smem + cur + 16384);
#pragma unroll
        for (int kk = 0; kk < 2; ++kk) {
            bf16x8 af[4], bv[4];
#pragma unroll
            for (int mi = 0; mi < 4; ++mi)
                af[mi] = *(const bf16x8*)(sA + SWZ(wm * 64 + mi * 16 + lrow, kk * 4 + kq));
#pragma unroll
            for (int ni = 0; ni < 4; ++ni)
                bv[ni] = *(const bf16x8*)(sB + SWZ(wn * 64 + ni * 16 + lrow, kk * 4 + kq));
#pragma unroll
            for (int mi = 0; mi < 4; ++mi)
#pragma unroll
                for (int ni = 0; ni < 4; ++ni)
                    acc[mi][ni] = __builtin_amdgcn_mfma_f32_16x16x32_bf16(af[mi], bv[ni], acc[mi][ni], 0, 0, 0);
        }
        __syncthreads();
    }

    int crow = (l >> 4) * 4;
    int ccol = l & 15;
    int gcolb = bn + wn * 64 + ccol * 4;   // 4 contiguous output columns
    float4 b4 = *(const float4*)(bias + gcolb);
#pragma unroll
    for (int mi = 0; mi < 4; ++mi) {
#pragma unroll
        for (int r = 0; r < 4; ++r) {
            int grow = bm + wm * 64 + mi * 16 + crow + r;
            size_t off = (size_t)grow * N + gcolb;
            float v0 = acc[mi][0][r] + b4.x;
            float v1 = acc[mi][1][r] + b4.y;
            float v2 = acc[mi][2][r] + b4.z;
            float v3 = acc[mi][3][r] + b4.w;
            if (EPI == 1) {
                float4 rr = *(const float4*)(resid + off);
                float4 o4 = {v0 + rr.x, v1 + rr.y, v2 + rr.z, v3 + rr.w};
                *(float4*)(Cf + off) = o4;
            } else {
                if (EPI == 2) {
                    v0 = gelu_f(v0); v1 = gelu_f(v1); v2 = gelu_f(v2); v3 = gelu_f(v3);
                }
                ushort4 o4 = {f2bf(v0), f2bf(v1), f2bf(v2), f2bf(v3)};
                *(ushort4*)(Cb + off) = o4;
            }
        }
    }
}

// ------------- MFMA GEMM 64x128: geometry-halved variant for N=1024 shapes -------------
// grid (8, M/64) = 512 blocks -> 2 blocks/CU.  LDS = 2 x (A 8KB + B 16KB) = 48KB.
template <int EPI>
__global__ __launch_bounds__(256, 2) void mgemm64(const unsigned short* __restrict__ A,
                                                  const unsigned short* __restrict__ BT,
                                                  const float* __restrict__ bias,
                                                  const float* __restrict__ resid,
                                                  float* __restrict__ Cf,
                                                  unsigned short* __restrict__ Cb,
                                                  int M, int N, int K)
{
    __shared__ char smem[49152];   // [2 bufs][A 8KB | B 16KB]
    int t = threadIdx.x;
    int bn = blockIdx.x * 128, bm = blockIdx.y * 64;
    int l = t & 63, w = t >> 6;       // 4 waves: 1M x 4N; per-wave C = 64x32
    int lrow = l & 15, kq = l >> 4;

    f32x4 acc[4][2];
#pragma unroll
    for (int i = 0; i < 4; ++i)
#pragma unroll
        for (int j = 0; j < 2; ++j) acc[i][j] = {0.f, 0.f, 0.f, 0.f};

    const unsigned short* Ap[2];
    int ldA[2];
#pragma unroll
    for (int i = 0; i < 2; ++i) {
        int cid = i * 256 + t;
        int row = cid >> 3, c = cid & 7;
        Ap[i] = A + (size_t)(bm + row) * K + ((c ^ (row & 7)) << 3);
        ldA[i] = cid << 4;
    }
    const unsigned short* Bp[4];
    int ldB[4];
#pragma unroll
    for (int i = 0; i < 4; ++i) {
        int cid = i * 256 + t;
        int row = cid >> 3, c = cid & 7;
        // 2-wide column interleave: LDS row (w*32 + ni*16 + lr) <- BT row (w*32 + lr*2 + ni)
        int prow = (row & ~31) + ((row & 15) << 1) + ((row >> 4) & 1);
        Bp[i] = BT + (size_t)(bn + prow) * K + ((c ^ (row & 7)) << 3);
        ldB[i] = cid << 4;
    }

    int nt = K >> 6;
#pragma unroll
    for (int i = 0; i < 2; ++i) gld16(smem + ldA[i], Ap[i]);
#pragma unroll
    for (int i = 0; i < 4; ++i) gld16(smem + 8192 + ldB[i], Bp[i]);
    __syncthreads();

    for (int tk = 0; tk < nt; ++tk) {
        int cur = (tk & 1) * 24576;
        if (tk + 1 < nt) {
            int k0 = (tk + 1) << 6;
            int nxt = 24576 - cur;
#pragma unroll
            for (int i = 0; i < 2; ++i) gld16(smem + nxt + ldA[i], Ap[i] + k0);
#pragma unroll
            for (int i = 0; i < 4; ++i) gld16(smem + nxt + 8192 + ldB[i], Bp[i] + k0);
        }
        const unsigned short* sA = (const unsigned short*)(smem + cur);
        const unsigned short* sB = (const unsigned short*)(smem + cur + 8192);
#pragma unroll
        for (int kk = 0; kk < 2; ++kk) {
            bf16x8 af[4], bv[2];
#pragma unroll
            for (int mi = 0; mi < 4; ++mi)
                af[mi] = *(const bf16x8*)(sA + SWZ(mi * 16 + lrow, kk * 4 + kq));
#pragma unroll
            for (int ni = 0; ni < 2; ++ni)
                bv[ni] = *(const bf16x8*)(sB + SWZ(w * 32 + ni * 16 + lrow, kk * 4 + kq));
#pragma unroll
            for (int mi = 0; mi < 4; ++mi)
#pragma unroll
                for (int ni = 0; ni < 2; ++ni)
                    acc[mi][ni] = __builtin_amdgcn_mfma_f32_16x16x32_bf16(af[mi], bv[ni], acc[mi][ni], 0, 0, 0);
        }
        __syncthreads();
    }

    int crow = (l >> 4) * 4;
    int ccol = l & 15;
    int gcolb = bn + w * 32 + ccol * 2;   // 2 contiguous output columns
    float2 b2 = *(const float2*)(bias + gcolb);
#pragma unroll
    for (int mi = 0; mi < 4; ++mi) {
#pragma unroll
        for (int r = 0; r < 4; ++r) {
            int grow = bm + mi * 16 + crow + r;
            size_t off = (size_t)grow * N + gcolb;
            float v0 = acc[mi][0][r] + b2.x;
            float v1 = acc[mi][1][r] + b2.y;
            if (EPI == 1) {
                float2 rr = *(const float2*)(resid + off);
                float2 o2 = {v0 + rr.x, v1 + rr.y};
                *(float2*)(Cf + off) = o2;
            } else {
                if (EPI == 2) { v0 = gelu_f(v0); v1 = gelu_f(v1); }
                *(unsigned*)(Cb + off) = pk2bf(v0, v1);
            }
        }
    }
}

// ---------------- MFMA flash attention v4 (best measured: 67.4us) ----------------
// 128 q-rows / 8 waves / block; reg-staged K+V prefetch across raw s_barrier;
// XCD pair-locality remap (FETCH 70->12MB).  Rounds 10-12 variants (setprio,
// tree-reduce, b64 P-write, K-gld16) all null or negative -> this exact form.
__global__ __launch_bounds__(512) void mattn(const unsigned short* __restrict__ qkv,
                                             unsigned short* __restrict__ out)
{
    __shared__ unsigned short Qs[128 * 64];       // [q][d] swizzled (16KB)
    __shared__ unsigned short Ks[2][64 * 64];     // [k][d] swizzled, dbuf (16KB)
    __shared__ unsigned short Vt[2][64 * 64];     // [d][k] swizzled, dbuf (16KB)
    __shared__ unsigned short Ps[8 * 16 * 64];    // per-wave [q16][k64] swizzled (16KB)
    int t = threadIdx.x;
    int w = t >> 6, l = t & 63;
    int lr = l & 15, lh = l >> 4;
    // XCD pair-locality remap (grid = 16 x 16 x 2 = 512 blocks, all co-resident)
    int hwid = blockIdx.x + (blockIdx.y << 4) + (blockIdx.z << 8);
    int xcd = hwid & 7, slot = hwid >> 3;
    int pair = (xcd << 2) + (slot >> 4);
    int q0 = (slot & 15) * 128;
    int hh = pair & 15, b = pair >> 4;
    const unsigned short* Qg = qkv + (size_t)b * SEQ * 3072 + hh * 64;
    const unsigned short* Kg = Qg + 1024;
    const unsigned short* Vg = Qg + 2048;

    // ---- stage Q via gld16 (pre-swizzled global source): 1024 chunks, 2/thread ----
#pragma unroll
    for (int i = 0; i < 2; ++i) {
        int chunkid = i * 512 + t;
        int row = chunkid >> 3, c = chunkid & 7;
        gld16(((char*)Qs) + chunkid * 16,
              Qg + (size_t)(q0 + row) * 3072 + ((c ^ (row & 7)) << 3));
    }

    // ---- K reg-staging: 512 chunks (64 rows x 8), 1 per thread ----
    int kr0 = t >> 3, kc0 = t & 7;
    const unsigned short* Kp0 = Kg + (size_t)kr0 * 3072 + kc0 * 8;
    int kd0 = SWZ(kr0, kc0);
    // ---- V: thread handles k-pair (vk,vk+1) x 4 d-elems ----
    int vk = (t & 31) * 2;
    int vd0 = ((t >> 5) & 15) * 4;
    const unsigned short* Vp0 = Vg + (size_t)vk * 3072 + vd0;
    const unsigned short* Vp1 = Vp0 + 3072;

    // prologue: load K/V tile 0 to regs
    u16x8 k0 = *(const u16x8*)Kp0;
    u16x4 v0 = *(const u16x4*)Vp0;
    u16x4 v1 = *(const u16x4*)Vp1;
    Kp0 += 64 * 3072; Vp0 += 64 * 3072; Vp1 += 64 * 3072;

    __syncthreads();   // Qs ready (full drain; prologue only)
    bf16x8 qa[2];
#pragma unroll
    for (int ks = 0; ks < 2; ++ks)
        qa[ks] = *(const bf16x8*)(Qs + SWZ(w * 16 + lr, ks * 4 + lh));

    // write tile 0 into buffer 0
    *(u16x8*)(Ks[0] + kd0) = k0;
#pragma unroll
    for (int j = 0; j < 4; ++j) {
        int d = vd0 + j;
        unsigned pack = (unsigned)(unsigned short)v0[j] | ((unsigned)(unsigned short)v1[j] << 16);
        *(unsigned*)(Vt[0] + SWZ(d, vk >> 3) + (vk & 7)) = pack;
    }
    // prefetch tile 1 to regs (stays in flight across the raw barrier)
    k0 = *(const u16x8*)Kp0;
    v0 = *(const u16x4*)Vp0; v1 = *(const u16x4*)Vp1;
    Kp0 += 64 * 3072; Vp0 += 64 * 3072; Vp1 += 64 * 3072;
    asm volatile("s_waitcnt lgkmcnt(0)" ::: "memory");   // publish buf0 writes
    __builtin_amdgcn_s_barrier();

    f32x4 o[4];
#pragma unroll
    for (int i = 0; i < 4; ++i) o[i] = {0.f, 0.f, 0.f, 0.f};
    float mr = -3.0e38f, lsum = 0.f;   // per-lane: q-row = w*16 + lr
    unsigned short* Pw = Ps + w * (16 * 64);
    const float C = 0.18033688011112042f;  // 0.125 * log2(e)

    const int nt = SEQ / 64;   // 32
    for (int tt = 0; tt < nt; ++tt) {
        const unsigned short* Kc = Ks[tt & 1];
        const unsigned short* Vc = Vt[tt & 1];

        // swapped QK^T: S^T = K·Q^T -> lane holds q=lr, k=ni*16+lh*4+r
        f32x4 s[4];
#pragma unroll
        for (int ni = 0; ni < 4; ++ni) s[ni] = {0.f, 0.f, 0.f, 0.f};
#pragma unroll
        for (int ks = 0; ks < 2; ++ks) {
#pragma unroll
            for (int ni = 0; ni < 4; ++ni) {
                bf16x8 kb = *(const bf16x8*)(Kc + SWZ(ni * 16 + lr, ks * 4 + lh));
                s[ni] = __builtin_amdgcn_mfma_f32_16x16x32_bf16(kb, qa[ks], s[ni], 0, 0, 0);
            }
        }
        // row max: 15 in-reg + 2 shfl (lanes sharing lr)
        float mx = s[0][0];
#pragma unroll
        for (int ni = 0; ni < 4; ++ni)
#pragma unroll
            for (int r = 0; r < 4; ++r) mx = fmaxf(mx, s[ni][r]);
        mx = fmaxf(mx, __shfl_xor(mx, 16));
        mx = fmaxf(mx, __shfl_xor(mx, 32));
        // defer-max: only rescale when growth beyond e^8 bound (always on tile 0)
        if (__any(mx > mr + 64.0f)) {
            float mn = fmaxf(mr, mx);
            float corr = fexp2((mr - mn) * C);
            mr = mn;
            lsum *= corr;
            float cr[4];
#pragma unroll
            for (int r = 0; r < 4; ++r) cr[r] = __shfl(corr, lh * 4 + r, 16);
#pragma unroll
            for (int nd = 0; nd < 4; ++nd) {
                o[nd][0] *= cr[0]; o[nd][1] *= cr[1];
                o[nd][2] *= cr[2]; o[nd][3] *= cr[3];
            }
        }
        float mc = mr * C;
        float rsum = 0.f;
#pragma unroll
        for (int ni = 0; ni < 4; ++ni)
#pragma unroll
            for (int r = 0; r < 4; ++r) {
                float p = fexp2(fmaf(s[ni][r], C, -mc));
                s[ni][r] = p;
                rsum += p;
            }
        rsum += __shfl_xor(rsum, 16);
        rsum += __shfl_xor(rsum, 32);
        lsum += rsum;
        // P write: packed pairs (adjacent k = r, r+1)
#pragma unroll
        for (int ni = 0; ni < 4; ++ni)
#pragma unroll
            for (int rp = 0; rp < 2; ++rp) {
                int k = ni * 16 + lh * 4 + rp * 2;
                *(unsigned*)(Pw + SWZ(lr, k >> 3) + (k & 7)) =
                    pk2bf(s[ni][rp * 2], s[ni][rp * 2 + 1]);
            }
        // PV: O[q16][d64] += P[q16][k64] @ V[k64][d64]
#pragma unroll
        for (int ks = 0; ks < 2; ++ks) {
            bf16x8 pa = *(const bf16x8*)(Pw + SWZ(lr, ks * 4 + lh));
#pragma unroll
            for (int nd = 0; nd < 4; ++nd) {
                bf16x8 vb = *(const bf16x8*)(Vc + SWZ(nd * 16 + lr, ks * 4 + lh));
                o[nd] = __builtin_amdgcn_mfma_f32_16x16x32_bf16(pa, vb, o[nd], 0, 0, 0);
            }
        }

        // ---- post-compute: write next tile's K/V (regs -> LDS), prefetch t+2 ----
        if (tt + 1 < nt) {
            int nb = (tt & 1) ^ 1;
            // implicit vmcnt wait here covers loads issued one full tile ago
            *(u16x8*)(Ks[nb] + kd0) = k0;
#pragma unroll
            for (int j = 0; j < 4; ++j) {
                int d = vd0 + j;
                unsigned pack = (unsigned)(unsigned short)v0[j] | ((unsigned)(unsigned short)v1[j] << 16);
                *(unsigned*)(Vt[nb] + SWZ(d, vk >> 3) + (vk & 7)) = pack;
            }
            if (tt + 2 < nt) {
                k0 = *(const u16x8*)Kp0;
                v0 = *(const u16x4*)Vp0; v1 = *(const u16x4*)Vp1;
                Kp0 += 64 * 3072; Vp0 += 64 * 3072; Vp1 += 64 * 3072;
            }
            asm volatile("s_waitcnt lgkmcnt(0)" ::: "memory");  // publish nb writes
            __builtin_amdgcn_s_barrier();                        // raw: no vmcnt drain
        }
    }
    // epilogue: redistribute 1/lsum to PV row owners
    float inv = 1.0f / lsum;
    float ir[4];
#pragma unroll
    for (int r = 0; r < 4; ++r) ir[r] = __shfl(inv, lh * 4 + r, 16);
#pragma unroll
    for (int r = 0; r < 4; ++r) {
        int q = q0 + w * 16 + lh * 4 + r;
#pragma unroll
        for (int nd = 0; nd < 4; ++nd) {
            int d = nd * 16 + lr;
            out[(size_t)((size_t)b * SEQ + q) * HDIM + hh * 64 + d] = f2bf(o[nd][r] * ir[r]);
        }
    }
}

extern "C" void kernel_launch(void* const* d_in, const int* in_sizes, int n_in,
                              void* d_out, int out_size, void* d_ws, size_t ws_size,
                              hipStream_t stream)
{
    const float* x     = (const float*)d_in[0];
    const float* ln1_g = (const float*)d_in[1];
    const float* ln1_b = (const float*)d_in[2];
    const float* W_qkv = (const float*)d_in[3];
    const float* b_qkv = (const float*)d_in[4];
    const float* W_out = (const float*)d_in[5];
    const float* b_out = (const float*)d_in[6];
    const float* ln2_g = (const float*)d_in[7];
    const float* ln2_b = (const float*)d_in[8];
    const float* W1    = (const float*)d_in[9];
    const float* b1    = (const float*)d_in[10];
    const float* W2    = (const float*)d_in[11];
    const float* b2    = (const float*)d_in[12];
    float* out = (float*)d_out;
    char* ws8  = (char*)d_ws;

    const int M = BATCH * SEQ;  // 4096
    const size_t MB = 1048576;

    unsigned short* hbuf = (unsigned short*)(ws8);
    unsigned short* qkvb = (unsigned short*)(ws8 + 8 * MB);
    unsigned short* attb = (unsigned short*)(ws8 + 32 * MB);
    unsigned short* ffn1 = (unsigned short*)(ws8 + 8 * MB);
    unsigned short* WqT  = (unsigned short*)(ws8 + 40 * MB);
    unsigned short* WoT  = (unsigned short*)(ws8 + 46 * MB);
    unsigned short* W1T  = (unsigned short*)(ws8 + 48 * MB);
    unsigned short* W2T  = (unsigned short*)(ws8 + 56 * MB);

    // merged: all 4 weight conversions (12288 blocks) + ln1 (4096 blocks) in ONE launch
    prep_kernel<<<16384, 256, 0, stream>>>(W_qkv, W_out, W1, W2, WqT, WoT, W1T, W2T,
                                           x, ln1_g, ln1_b, hbuf);
    // QKV: 128x128, grid 24x32 = 768 blocks
    mgemm<0><<<dim3(3 * HDIM / 128, M / 128), 256, 0, stream>>>(hbuf, WqT, b_qkv, nullptr, nullptr, qkvb, M, 3 * HDIM, HDIM);
    mattn<<<dim3(SEQ / 128, NHEAD, BATCH), 512, 0, stream>>>(qkvb, attb);
    // out-proj: 64x128, grid 8x64 = 512 blocks (exact fill), fused residual
    mgemm64<1><<<dim3(HDIM / 128, M / 64), 256, 0, stream>>>(attb, WoT, b_out, x, out, nullptr, M, HDIM, HDIM);
    ln_kernel<<<M, 256, 0, stream>>>(out, ln2_g, ln2_b, hbuf);
    // FFN1: 128x128, grid 32x32 = 1024 blocks (2 exact fills), fused gelu
    mgemm<2><<<dim3(4 * HDIM / 128, M / 128), 256, 0, stream>>>(hbuf, W1T, b1, nullptr, nullptr, ffn1, M, 4 * HDIM, HDIM);
    // FFN2: 64x128, grid 8x64 = 512 blocks (exact fill), fused residual (in-place on out)
    mgemm64<1><<<dim3(HDIM / 128, M / 64), 256, 0, stream>>>(ffn1, W2T, b2, out, out, nullptr, M, HDIM, 4 * HDIM);
}

// Round 17
// 216.342 us; speedup vs baseline: 1.0171x; 1.0016x over previous
//
#include <hip/hip_runtime.h>
#include <hip/hip_bf16.h>
#include <math.h>

#define HDIM 1024
#define SEQ  2048
#define BATCH 2
#define NHEAD 16
#define HEADD 64

typedef short bf16x8 __attribute__((ext_vector_type(8)));
typedef float f32x4  __attribute__((ext_vector_type(4)));
typedef unsigned short u16x8 __attribute__((ext_vector_type(8)));
typedef unsigned short u16x4 __attribute__((ext_vector_type(4)));

__device__ __forceinline__ unsigned short f2bf(float f) {
    unsigned u = __float_as_uint(f);
    unsigned r = (u + 0x7FFFu + ((u >> 16) & 1u)) >> 16;
    return (unsigned short)r;
}
__device__ __forceinline__ unsigned pk2bf(float lo, float hi) {
    __hip_bfloat162 h = __float22bfloat162_rn(float2{lo, hi});
    unsigned r;
    __builtin_memcpy(&r, &h, 4);
    return r;
}
__device__ __forceinline__ float fexp2(float x) {
#if __has_builtin(__builtin_amdgcn_exp2f)
    return __builtin_amdgcn_exp2f(x);
#else
    return exp2f(x);
#endif
}
__device__ __forceinline__ float frcp(float x) {
#if __has_builtin(__builtin_amdgcn_rcpf)
    return __builtin_amdgcn_rcpf(x);
#else
    return 1.0f / x;
#endif
}
// Abramowitz-Stegun 7.1.26 erf, |err| < 1.5e-7 (exact at bf16 precision)
__device__ __forceinline__ float erf_fast(float x) {
    float ax = fabsf(x);
    float t = frcp(fmaf(0.3275911f, ax, 1.0f));
    float p = fmaf(t, 1.061405429f, -1.453152027f);
    p = fmaf(p, t, 1.421413741f);
    p = fmaf(p, t, -0.284496736f);
    p = fmaf(p, t, 0.254829592f);
    p *= t;
    float e = fexp2(ax * ax * -1.4426950408889634f);
    return copysignf(fmaf(-p, e, 1.0f), x);
}
__device__ __forceinline__ float gelu_f(float v) {
    return 0.5f * v * (1.0f + erf_fast(v * 0.70710678118654752f));
}
__device__ __forceinline__ void gld16(void* lds, const void* g) {
    __builtin_amdgcn_global_load_lds(
        (const __attribute__((address_space(1))) unsigned int*)(g),
        (__attribute__((address_space(3))) unsigned int*)(lds),
        16, 0, 0);
}

// swizzled element offset for row-major [*][64] bf16 tiles (128B rows, 8 chunks of 16B)
#define SWZ(row, chunk) (((row) * 64) + (((chunk) ^ ((row) & 7)) << 3))

// ---------------- LayerNorm: fp32 in, bf16 out ----------------
__global__ __launch_bounds__(256) void ln_kernel(const float* __restrict__ x,
                                                 const float* __restrict__ gw,
                                                 const float* __restrict__ bw,
                                                 unsigned short* __restrict__ y)
{
    int row = blockIdx.x;
    int t = threadIdx.x;
    const float* xr = x + (size_t)row * HDIM;
    float4 v = *(const float4*)(xr + t * 4);
    float s1 = v.x + v.y + v.z + v.w;
    float s2 = v.x * v.x + v.y * v.y + v.z * v.z + v.w * v.w;
#pragma unroll
    for (int m = 1; m < 64; m <<= 1) {
        s1 += __shfl_xor(s1, m);
        s2 += __shfl_xor(s2, m);
    }
    __shared__ float red[8];
    int wid = t >> 6;
    if ((t & 63) == 0) { red[wid * 2] = s1; red[wid * 2 + 1] = s2; }
    __syncthreads();
    if (t == 0) {
        float a = red[0] + red[2] + red[4] + red[6];
        float b = red[1] + red[3] + red[5] + red[7];
        red[0] = a; red[1] = b;
    }
    __syncthreads();
    float mu  = red[0] * (1.0f / HDIM);
    float var = red[1] * (1.0f / HDIM) - mu * mu;
    float rs  = rsqrtf(var + 1e-5f);
    float4 g4 = *(const float4*)(gw + t * 4);
    float4 b4 = *(const float4*)(bw + t * 4);
    ushort4 o;
    o.x = f2bf((v.x - mu) * rs * g4.x + b4.x);
    o.y = f2bf((v.y - mu) * rs * g4.y + b4.y);
    o.z = f2bf((v.z - mu) * rs * g4.z + b4.z);
    o.w = f2bf((v.w - mu) * rs * g4.w + b4.w);
    *(ushort4*)(y + (size_t)row * HDIM + t * 4) = o;
}

// ------- merged prep: weight fp32->bf16^T (blocks 0..12287) + ln1 (blocks 12288..16383) ----
// Both depend only on kernel inputs -> fusing removes one serialized launch boundary.
__global__ __launch_bounds__(256) void prep_kernel(const float* __restrict__ Wq,
                                                   const float* __restrict__ Wo,
                                                   const float* __restrict__ W1,
                                                   const float* __restrict__ W2,
                                                   unsigned short* __restrict__ WqT,
                                                   unsigned short* __restrict__ WoT,
                                                   unsigned short* __restrict__ W1T,
                                                   unsigned short* __restrict__ W2T,
                                                   const float* __restrict__ x,
                                                   const float* __restrict__ gw,
                                                   const float* __restrict__ bw,
                                                   unsigned short* __restrict__ y)
{
    __shared__ float tile[32][33];
    int bid = blockIdx.x;
    int t = threadIdx.x;

    if (bid >= 12288) {
        // ---- LayerNorm row (x -> y), identical to ln_kernel ----
        int row = bid - 12288;
        const float* xr = x + (size_t)row * HDIM;
        float4 v = *(const float4*)(xr + t * 4);
        float s1 = v.x + v.y + v.z + v.w;
        float s2 = v.x * v.x + v.y * v.y + v.z * v.z + v.w * v.w;
#pragma unroll
        for (int m = 1; m < 64; m <<= 1) {
            s1 += __shfl_xor(s1, m);
            s2 += __shfl_xor(s2, m);
        }
        float* red = &tile[0][0];
        int wid = t >> 6;
        if ((t & 63) == 0) { red[wid * 2] = s1; red[wid * 2 + 1] = s2; }
        __syncthreads();
        if (t == 0) {
            float a = red[0] + red[2] + red[4] + red[6];
            float b = red[1] + red[3] + red[5] + red[7];
            red[0] = a; red[1] = b;
        }
        __syncthreads();
        float mu  = red[0] * (1.0f / HDIM);
        float var = red[1] * (1.0f / HDIM) - mu * mu;
        float rs  = rsqrtf(var + 1e-5f);
        float4 g4 = *(const float4*)(gw + t * 4);
        float4 b4 = *(const float4*)(bw + t * 4);
        ushort4 o;
        o.x = f2bf((v.x - mu) * rs * g4.x + b4.x);
        o.y = f2bf((v.y - mu) * rs * g4.y + b4.y);
        o.z = f2bf((v.z - mu) * rs * g4.z + b4.z);
        o.w = f2bf((v.w - mu) * rs * g4.w + b4.w);
        *(ushort4*)(y + (size_t)row * HDIM + t * 4) = o;
        return;
    }

    // ---- weight conversion tile, identical to wconv_all ----
    const float* W; unsigned short* WT; int K, nx, idx;
    if (bid < 3072)      { W = Wq; WT = WqT; K = 1024; nx = 96;  idx = bid; }
    else if (bid < 4096) { W = Wo; WT = WoT; K = 1024; nx = 32;  idx = bid - 3072; }
    else if (bid < 8192) { W = W1; WT = W1T; K = 1024; nx = 128; idx = bid - 4096; }
    else                 { W = W2; WT = W2T; K = 4096; nx = 32;  idx = bid - 8192; }
    int N = nx * 32;
    int n0 = (idx % nx) * 32, k0 = (idx / nx) * 32;

    int c = t & 31, r = t >> 5;
#pragma unroll
    for (int i = 0; i < 4; ++i)
        tile[r + 8 * i][c] = W[(size_t)(k0 + r + 8 * i) * N + n0 + c];
    __syncthreads();
#pragma unroll
    for (int i = 0; i < 4; ++i)
        WT[(size_t)(n0 + r + 8 * i) * K + k0 + c] = f2bf(tile[c][r + 8 * i]);
}

// ------------- MFMA GEMM 128x128: BK=64, dbuf LDS 64KB, 1 barrier/K-tile -------------
// Round-1 verified structure (0 bank conflicts), default block mapping.
// B-column interleave: lane's 4 ni-accumulators = 4 contiguous output columns
// -> vector epilogue (16 x ushort4/float4 stores).
template <int EPI>
__global__ __launch_bounds__(256, 2) void mgemm(const unsigned short* __restrict__ A,
                                                const unsigned short* __restrict__ BT,
                                                const float* __restrict__ bias,
                                                const float* __restrict__ resid,
                                                float* __restrict__ Cf,
                                                unsigned short* __restrict__ Cb,
                                                int M, int N, int K)
{
    __shared__ char smem[65536];   // [2 bufs][A 16KB | B 16KB]
    int t = threadIdx.x;
    int bn = blockIdx.x * 128, bm = blockIdx.y * 128;
    int l = t & 63, w = t >> 6;
    int wm = w >> 1, wn = w & 1;
    int lrow = l & 15, kq = l >> 4;

    f32x4 acc[4][4];
#pragma unroll
    for (int i = 0; i < 4; ++i)
#pragma unroll
        for (int j = 0; j < 4; ++j) acc[i][j] = {0.f, 0.f, 0.f, 0.f};

    const unsigned short* Ap[4];
    const unsigned short* Bp[4];
    int ld[4];
#pragma unroll
    for (int i = 0; i < 4; ++i) {
        int cid = i * 256 + t;
        int row = cid >> 3, c = cid & 7;
        int gc = (c ^ (row & 7)) << 3;
        Ap[i] = A + (size_t)(bm + row) * K + gc;
        // B-column interleave: LDS row -> permuted BT row
        int prow = (row & 64) + ((row & 15) << 2) + ((row >> 4) & 3);
        Bp[i] = BT + (size_t)(bn + prow) * K + gc;
        ld[i] = cid << 4;
    }

    int nt = K >> 6;
#pragma unroll
    for (int i = 0; i < 4; ++i) {
        gld16(smem + ld[i], Ap[i]);
        gld16(smem + 16384 + ld[i], Bp[i]);
    }
    __syncthreads();

    for (int tk = 0; tk < nt; ++tk) {
        int cur = (tk & 1) << 15;
        if (tk + 1 < nt) {
            int k0 = (tk + 1) << 6;
            int nxt = 32768 - cur;
#pragma unroll
            for (int i = 0; i < 4; ++i) {
                gld16(smem + nxt + ld[i], Ap[i] + k0);
                gld16(smem + nxt + 16384 + ld[i], Bp[i] + k0);
            }
        }
        const unsigned short* sA = (const unsigned short*)(smem + cur);
        const unsigned short* sB = (const unsigned short*)(smem + cur + 16384);
#pragma unroll
        for (int kk = 0; kk < 2; ++kk) {
            bf16x8 af[4], bv[4];
#pragma unroll
            for (int mi = 0; mi < 4; ++mi)
                af[mi] = *(const bf16x8*)(sA + SWZ(wm * 64 + mi * 16 + lrow, kk * 4 + kq));
#pragma unroll
            for (int ni = 0; ni < 4; ++ni)
                bv[ni] = *(const bf16x8*)(sB + SWZ(wn * 64 + ni * 16 + lrow, kk * 4 + kq));
#pragma unroll
            for (int mi = 0; mi < 4; ++mi)
#pragma unroll
                for (int ni = 0; ni < 4; ++ni)
                    acc[mi][ni] = __builtin_amdgcn_mfma_f32_16x16x32_bf16(af[mi], bv[ni], acc[mi][ni], 0, 0, 0);
        }
        __syncthreads();
    }

    int crow = (l >> 4) * 4;
    int ccol = l & 15;
    int gcolb = bn + wn * 64 + ccol * 4;   // 4 contiguous output columns
    float4 b4 = *(const float4*)(bias + gcolb);
#pragma unroll
    for (int mi = 0; mi < 4; ++mi) {
#pragma unroll
        for (int r = 0; r < 4; ++r) {
            int grow = bm + wm * 64 + mi * 16 + crow + r;
            size_t off = (size_t)grow * N + gcolb;
            float v0 = acc[mi][0][r] + b4.x;
            float v1 = acc[mi][1][r] + b4.y;
            float v2 = acc[mi][2][r] + b4.z;
            float v3 = acc[mi][3][r] + b4.w;
            if (EPI == 1) {
                float4 rr = *(const float4*)(resid + off);
                float4 o4 = {v0 + rr.x, v1 + rr.y, v2 + rr.z, v3 + rr.w};
                *(float4*)(Cf + off) = o4;
            } else {
                if (EPI == 2) {
                    v0 = gelu_f(v0); v1 = gelu_f(v1); v2 = gelu_f(v2); v3 = gelu_f(v3);
                }
                ushort4 o4 = {f2bf(v0), f2bf(v1), f2bf(v2), f2bf(v3)};
                *(ushort4*)(Cb + off) = o4;
            }
        }
    }
}

// ------------- MFMA GEMM 64x128: geometry-halved variant for N=1024 shapes -------------
// grid (8, M/64) = 512 blocks -> 2 blocks/CU.  LDS = 2 x (A 8KB + B 16KB) = 48KB.
template <int EPI>
__global__ __launch_bounds__(256, 2) void mgemm64(const unsigned short* __restrict__ A,
                                                  const unsigned short* __restrict__ BT,
                                                  const float* __restrict__ bias,
                                                  const float* __restrict__ resid,
                                                  float* __restrict__ Cf,
                                                  unsigned short* __restrict__ Cb,
                                                  int M, int N, int K)
{
    __shared__ char smem[49152];   // [2 bufs][A 8KB | B 16KB]
    int t = threadIdx.x;
    int bn = blockIdx.x * 128, bm = blockIdx.y * 64;
    int l = t & 63, w = t >> 6;       // 4 waves: 1M x 4N; per-wave C = 64x32
    int lrow = l & 15, kq = l >> 4;

    f32x4 acc[4][2];
#pragma unroll
    for (int i = 0; i < 4; ++i)
#pragma unroll
        for (int j = 0; j < 2; ++j) acc[i][j] = {0.f, 0.f, 0.f, 0.f};

    const unsigned short* Ap[2];
    int ldA[2];
#pragma unroll
    for (int i = 0; i < 2; ++i) {
        int cid = i * 256 + t;
        int row = cid >> 3, c = cid & 7;
        Ap[i] = A + (size_t)(bm + row) * K + ((c ^ (row & 7)) << 3);
        ldA[i] = cid << 4;
    }
    const unsigned short* Bp[4];
    int ldB[4];
#pragma unroll
    for (int i = 0; i < 4; ++i) {
        int cid = i * 256 + t;
        int row = cid >> 3, c = cid & 7;
        // 2-wide column interleave: LDS row (w*32 + ni*16 + lr) <- BT row (w*32 + lr*2 + ni)
        int prow = (row & ~31) + ((row & 15) << 1) + ((row >> 4) & 1);
        Bp[i] = BT + (size_t)(bn + prow) * K + ((c ^ (row & 7)) << 3);
        ldB[i] = cid << 4;
    }

    int nt = K >> 6;
#pragma unroll
    for (int i = 0; i < 2; ++i) gld16(smem + ldA[i], Ap[i]);
#pragma unroll
    for (int i = 0; i < 4; ++i) gld16(smem + 8192 + ldB[i], Bp[i]);
    __syncthreads();

    for (int tk = 0; tk < nt; ++tk) {
        int cur = (tk & 1) * 24576;
        if (tk + 1 < nt) {
            int k0 = (tk + 1) << 6;
            int nxt = 24576 - cur;
#pragma unroll
            for (int i = 0; i < 2; ++i) gld16(smem + nxt + ldA[i], Ap[i] + k0);
#pragma unroll
            for (int i = 0; i < 4; ++i) gld16(smem + nxt + 8192 + ldB[i], Bp[i] + k0);
        }
        const unsigned short* sA = (const unsigned short*)(smem + cur);
        const unsigned short* sB = (const unsigned short*)(smem + cur + 8192);
#pragma unroll
        for (int kk = 0; kk < 2; ++kk) {
            bf16x8 af[4], bv[2];
#pragma unroll
            for (int mi = 0; mi < 4; ++mi)
                af[mi] = *(const bf16x8*)(sA + SWZ(mi * 16 + lrow, kk * 4 + kq));
#pragma unroll
            for (int ni = 0; ni < 2; ++ni)
                bv[ni] = *(const bf16x8*)(sB + SWZ(w * 32 + ni * 16 + lrow, kk * 4 + kq));
#pragma unroll
            for (int mi = 0; mi < 4; ++mi)
#pragma unroll
                for (int ni = 0; ni < 2; ++ni)
                    acc[mi][ni] = __builtin_amdgcn_mfma_f32_16x16x32_bf16(af[mi], bv[ni], acc[mi][ni], 0, 0, 0);
        }
        __syncthreads();
    }

    int crow = (l >> 4) * 4;
    int ccol = l & 15;
    int gcolb = bn + w * 32 + ccol * 2;   // 2 contiguous output columns
    float2 b2 = *(const float2*)(bias + gcolb);
#pragma unroll
    for (int mi = 0; mi < 4; ++mi) {
#pragma unroll
        for (int r = 0; r < 4; ++r) {
            int grow = bm + mi * 16 + crow + r;
            size_t off = (size_t)grow * N + gcolb;
            float v0 = acc[mi][0][r] + b2.x;
            float v1 = acc[mi][1][r] + b2.y;
            if (EPI == 1) {
                float2 rr = *(const float2*)(resid + off);
                float2 o2 = {v0 + rr.x, v1 + rr.y};
                *(float2*)(Cf + off) = o2;
            } else {
                if (EPI == 2) { v0 = gelu_f(v0); v1 = gelu_f(v1); }
                *(unsigned*)(Cb + off) = pk2bf(v0, v1);
            }
        }
    }
}

// ---------------- MFMA flash attention v4 (best measured: 67.4us) ----------------
// 128 q-rows / 8 waves / block; reg-staged K+V prefetch across raw s_barrier;
// XCD pair-locality remap (FETCH 70->12MB).  Rounds 10-12 variants (setprio,
// tree-reduce, b64 P-write, K-gld16) all null or negative -> this exact form.
__global__ __launch_bounds__(512) void mattn(const unsigned short* __restrict__ qkv,
                                             unsigned short* __restrict__ out)
{
    __shared__ unsigned short Qs[128 * 64];       // [q][d] swizzled (16KB)
    __shared__ unsigned short Ks[2][64 * 64];     // [k][d] swizzled, dbuf (16KB)
    __shared__ unsigned short Vt[2][64 * 64];     // [d][k] swizzled, dbuf (16KB)
    __shared__ unsigned short Ps[8 * 16 * 64];    // per-wave [q16][k64] swizzled (16KB)
    int t = threadIdx.x;
    int w = t >> 6, l = t & 63;
    int lr = l & 15, lh = l >> 4;
    // XCD pair-locality remap (grid = 16 x 16 x 2 = 512 blocks, all co-resident)
    int hwid = blockIdx.x + (blockIdx.y << 4) + (blockIdx.z << 8);
    int xcd = hwid & 7, slot = hwid >> 3;
    int pair = (xcd << 2) + (slot >> 4);
    int q0 = (slot & 15) * 128;
    int hh = pair & 15, b = pair >> 4;
    const unsigned short* Qg = qkv + (size_t)b * SEQ * 3072 + hh * 64;
    const unsigned short* Kg = Qg + 1024;
    const unsigned short* Vg = Qg + 2048;

    // ---- stage Q via gld16 (pre-swizzled global source): 1024 chunks, 2/thread ----
#pragma unroll
    for (int i = 0; i < 2; ++i) {
        int chunkid = i * 512 + t;
        int row = chunkid >> 3, c = chunkid & 7;
        gld16(((char*)Qs) + chunkid * 16,
              Qg + (size_t)(q0 + row) * 3072 + ((c ^ (row & 7)) << 3));
    }

    // ---- K reg-staging: 512 chunks (64 rows x 8), 1 per thread ----
    int kr0 = t >> 3, kc0 = t & 7;
    const unsigned short* Kp0 = Kg + (size_t)kr0 * 3072 + kc0 * 8;
    int kd0 = SWZ(kr0, kc0);
    // ---- V: thread handles k-pair (vk,vk+1) x 4 d-elems ----
    int vk = (t & 31) * 2;
    int vd0 = ((t >> 5) & 15) * 4;
    const unsigned short* Vp0 = Vg + (size_t)vk * 3072 + vd0;
    const unsigned short* Vp1 = Vp0 + 3072;

    // prologue: load K/V tile 0 to regs
    u16x8 k0 = *(const u16x8*)Kp0;
    u16x4 v0 = *(const u16x4*)Vp0;
    u16x4 v1 = *(const u16x4*)Vp1;
    Kp0 += 64 * 3072; Vp0 += 64 * 3072; Vp1 += 64 * 3072;

    __syncthreads();   // Qs ready (full drain; prologue only)
    bf16x8 qa[2];
#pragma unroll
    for (int ks = 0; ks < 2; ++ks)
        qa[ks] = *(const bf16x8*)(Qs + SWZ(w * 16 + lr, ks * 4 + lh));

    // write tile 0 into buffer 0
    *(u16x8*)(Ks[0] + kd0) = k0;
#pragma unroll
    for (int j = 0; j < 4; ++j) {
        int d = vd0 + j;
        unsigned pack = (unsigned)(unsigned short)v0[j] | ((unsigned)(unsigned short)v1[j] << 16);
        *(unsigned*)(Vt[0] + SWZ(d, vk >> 3) + (vk & 7)) = pack;
    }
    // prefetch tile 1 to regs (stays in flight across the raw barrier)
    k0 = *(const u16x8*)Kp0;
    v0 = *(const u16x4*)Vp0; v1 = *(const u16x4*)Vp1;
    Kp0 += 64 * 3072; Vp0 += 64 * 3072; Vp1 += 64 * 3072;
    asm volatile("s_waitcnt lgkmcnt(0)" ::: "memory");   // publish buf0 writes
    __builtin_amdgcn_s_barrier();

    f32x4 o[4];
#pragma unroll
    for (int i = 0; i < 4; ++i) o[i] = {0.f, 0.f, 0.f, 0.f};
    float mr = -3.0e38f, lsum = 0.f;   // per-lane: q-row = w*16 + lr
    unsigned short* Pw = Ps + w * (16 * 64);
    const float C = 0.18033688011112042f;  // 0.125 * log2(e)

    const int nt = SEQ / 64;   // 32
    for (int tt = 0; tt < nt; ++tt) {
        const unsigned short* Kc = Ks[tt & 1];
        const unsigned short* Vc = Vt[tt & 1];

        // swapped QK^T: S^T = K·Q^T -> lane holds q=lr, k=ni*16+lh*4+r
        f32x4 s[4];
#pragma unroll
        for (int ni = 0; ni < 4; ++ni) s[ni] = {0.f, 0.f, 0.f, 0.f};
#pragma unroll
        for (int ks = 0; ks < 2; ++ks) {
#pragma unroll
            for (int ni = 0; ni < 4; ++ni) {
                bf16x8 kb = *(const bf16x8*)(Kc + SWZ(ni * 16 + lr, ks * 4 + lh));
                s[ni] = __builtin_amdgcn_mfma_f32_16x16x32_bf16(kb, qa[ks], s[ni], 0, 0, 0);
            }
        }
        // row max: 15 in-reg + 2 shfl (lanes sharing lr)
        float mx = s[0][0];
#pragma unroll
        for (int ni = 0; ni < 4; ++ni)
#pragma unroll
            for (int r = 0; r < 4; ++r) mx = fmaxf(mx, s[ni][r]);
        mx = fmaxf(mx, __shfl_xor(mx, 16));
        mx = fmaxf(mx, __shfl_xor(mx, 32));
        // defer-max: only rescale when growth beyond e^8 bound (always on tile 0)
        if (__any(mx > mr + 64.0f)) {
            float mn = fmaxf(mr, mx);
            float corr = fexp2((mr - mn) * C);
            mr = mn;
            lsum *= corr;
            float cr[4];
#pragma unroll
            for (int r = 0; r < 4; ++r) cr[r] = __shfl(corr, lh * 4 + r, 16);
#pragma unroll
            for (int nd = 0; nd < 4; ++nd) {
                o[nd][0] *= cr[0]; o[nd][1] *= cr[1];
                o[nd][2] *= cr[2]; o[nd][3] *= cr[3];
            }
        }
        float mc = mr * C;
        float rsum = 0.f;
#pragma unroll
        for (int ni = 0; ni < 4; ++ni)
#pragma unroll
            for (int r = 0; r < 4; ++r) {
                float p = fexp2(fmaf(s[ni][r], C, -mc));
                s[ni][r] = p;
                rsum += p;
            }
        rsum += __shfl_xor(rsum, 16);
        rsum += __shfl_xor(rsum, 32);
        lsum += rsum;
        // P write: packed pairs (adjacent k = r, r+1)
#pragma unroll
        for (int ni = 0; ni < 4; ++ni)
#pragma unroll
            for (int rp = 0; rp < 2; ++rp) {
                int k = ni * 16 + lh * 4 + rp * 2;
                *(unsigned*)(Pw + SWZ(lr, k >> 3) + (k & 7)) =
                    pk2bf(s[ni][rp * 2], s[ni][rp * 2 + 1]);
            }
        // PV: O[q16][d64] += P[q16][k64] @ V[k64][d64]
#pragma unroll
        for (int ks = 0; ks < 2; ++ks) {
            bf16x8 pa = *(const bf16x8*)(Pw + SWZ(lr, ks * 4 + lh));
#pragma unroll
            for (int nd = 0; nd < 4; ++nd) {
                bf16x8 vb = *(const bf16x8*)(Vc + SWZ(nd * 16 + lr, ks * 4 + lh));
                o[nd] = __builtin_amdgcn_mfma_f32_16x16x32_bf16(pa, vb, o[nd], 0, 0, 0);
            }
        }

        // ---- post-compute: write next tile's K/V (regs -> LDS), prefetch t+2 ----
        if (tt + 1 < nt) {
            int nb = (tt & 1) ^ 1;
            // implicit vmcnt wait here covers loads issued one full tile ago
            *(u16x8*)(Ks[nb] + kd0) = k0;
#pragma unroll
            for (int j = 0; j < 4; ++j) {
                int d = vd0 + j;
                unsigned pack = (unsigned)(unsigned short)v0[j] | ((unsigned)(unsigned short)v1[j] << 16);
                *(unsigned*)(Vt[nb] + SWZ(d, vk >> 3) + (vk & 7)) = pack;
            }
            if (tt + 2 < nt) {
                k0 = *(const u16x8*)Kp0;
                v0 = *(const u16x4*)Vp0; v1 = *(const u16x4*)Vp1;
                Kp0 += 64 * 3072; Vp0 += 64 * 3072; Vp1 += 64 * 3072;
            }
            asm volatile("s_waitcnt lgkmcnt(0)" ::: "memory");  // publish nb writes
            __builtin_amdgcn_s_barrier();                        // raw: no vmcnt drain
        }
    }
    // epilogue: redistribute 1/lsum to PV row owners
    float inv = 1.0f / lsum;
    float ir[4];
#pragma unroll
    for (int r = 0; r < 4; ++r) ir[r] = __shfl(inv, lh * 4 + r, 16);
#pragma unroll
    for (int r = 0; r < 4; ++r) {
        int q = q0 + w * 16 + lh * 4 + r;
#pragma unroll
        for (int nd = 0; nd < 4; ++nd) {
            int d = nd * 16 + lr;
            out[(size_t)((size_t)b * SEQ + q) * HDIM + hh * 64 + d] = f2bf(o[nd][r] * ir[r]);
        }
    }
}

extern "C" void kernel_launch(void* const* d_in, const int* in_sizes, int n_in,
                              void* d_out, int out_size, void* d_ws, size_t ws_size,
                              hipStream_t stream)
{
    const float* x     = (const float*)d_in[0];
    const float* ln1_g = (const float*)d_in[1];
    const float* ln1_b = (const float*)d_in[2];
    const float* W_qkv = (const float*)d_in[3];
    const float* b_qkv = (const float*)d_in[4];
    const float* W_out = (const float*)d_in[5];
    const float* b_out = (const float*)d_in[6];
    const float* ln2_g = (const float*)d_in[7];
    const float* ln2_b = (const float*)d_in[8];
    const float* W1    = (const float*)d_in[9];
    const float* b1    = (const float*)d_in[10];
    const float* W2    = (const float*)d_in[11];
    const float* b2    = (const float*)d_in[12];
    float* out = (float*)d_out;
    char* ws8  = (char*)d_ws;

    const int M = BATCH * SEQ;  // 4096
    const size_t MB = 1048576;

    unsigned short* hbuf = (unsigned short*)(ws8);
    unsigned short* qkvb = (unsigned short*)(ws8 + 8 * MB);
    unsigned short* attb = (unsigned short*)(ws8 + 32 * MB);
    unsigned short* ffn1 = (unsigned short*)(ws8 + 8 * MB);
    unsigned short* WqT  = (unsigned short*)(ws8 + 40 * MB);
    unsigned short* WoT  = (unsigned short*)(ws8 + 46 * MB);
    unsigned short* W1T  = (unsigned short*)(ws8 + 48 * MB);
    unsigned short* W2T  = (unsigned short*)(ws8 + 56 * MB);

    // merged: all 4 weight conversions (12288 blocks) + ln1 (4096 blocks) in ONE launch
    prep_kernel<<<16384, 256, 0, stream>>>(W_qkv, W_out, W1, W2, WqT, WoT, W1T, W2T,
                                           x, ln1_g, ln1_b, hbuf);
    // QKV: 128x128, grid 24x32 = 768 blocks
    mgemm<0><<<dim3(3 * HDIM / 128, M / 128), 256, 0, stream>>>(hbuf, WqT, b_qkv, nullptr, nullptr, qkvb, M, 3 * HDIM, HDIM);
    mattn<<<dim3(SEQ / 128, NHEAD, BATCH), 512, 0, stream>>>(qkvb, attb);
    // out-proj: 64x128, grid 8x64 = 512 blocks (exact fill), fused residual
    mgemm64<1><<<dim3(HDIM / 128, M / 64), 256, 0, stream>>>(attb, WoT, b_out, x, out, nullptr, M, HDIM, HDIM);
    ln_kernel<<<M, 256, 0, stream>>>(out, ln2_g, ln2_b, hbuf);
    // FFN1: 128x128, grid 32x32 = 1024 blocks (2 exact fills), fused gelu
    mgemm<2><<<dim3(4 * HDIM / 128, M / 128), 256, 0, stream>>>(hbuf, W1T, b1, nullptr, nullptr, ffn1, M, 4 * HDIM, HDIM);
    // FFN2: 64x128, grid 8x64 = 512 blocks (exact fill), fused residual (in-place on out)
    mgemm64<1><<<dim3(HDIM / 128, M / 64), 256, 0, stream>>>(ffn1, W2T, b2, out, out, nullptr, M, HDIM, 4 * HDIM);
}